// Round 4
// baseline (4132.858 us; speedup 1.0000x reference)
//
#include <hip/hip_runtime.h>
#include <hip/hip_bf16.h>

#define B_   1024
#define H_   512
#define L_   256
#define O_   128
#define SEQ_ 100
#define TE_  200
#define RS   72    // LDS row stride (ushorts) for 64-wide bf16 tiles (+8 pad)
#define AR   264   // LDS row stride (ushorts) for 256-wide bf16 tiles (+8 pad)

typedef __attribute__((ext_vector_type(8))) short short8;
typedef __attribute__((ext_vector_type(4))) float f32x4;

__device__ __forceinline__ float sigmoidf_(float x) { return 1.f / (1.f + __expf(-x)); }
__device__ __forceinline__ float tanhf_(float x) { return 1.f - 2.f / (__expf(2.f * x) + 1.f); }
__device__ __forceinline__ unsigned short f2bf(float x) {
    union { float f; unsigned u; } c; c.f = x;
    unsigned r = c.u + 0x7fffu + ((c.u >> 16) & 1u);   // RNE
    return (unsigned short)(r >> 16);
}
__device__ __forceinline__ float bf2f(unsigned short u) {
    union { unsigned u; float f; } c; c.u = (unsigned)u << 16; return c.f;
}
__device__ __forceinline__ unsigned relu2bf(unsigned x) {
    unsigned hi = x & 0xFFFF0000u, lo = x & 0x0000FFFFu;
    if (x & 0x80000000u) hi = 0u;
    if (x & 0x00008000u) lo = 0u;
    return hi | lo;
}
__device__ __forceinline__ uint4 relu8bf(uint4 v) {
    v.x = relu2bf(v.x); v.y = relu2bf(v.y); v.z = relu2bf(v.z); v.w = relu2bf(v.w);
    return v;
}

// ---------------------------------------------------------------------------
// fp32 -> bf16 convert (n4 = count/4) — used for small weights only
// ---------------------------------------------------------------------------
__global__ void k_cvt(const float* __restrict__ s, unsigned short* __restrict__ d, int n4) {
    int i = blockIdx.x * 256 + threadIdx.x;
    if (i < n4) {
        float4 v = ((const float4*)s)[i];
        ushort4 o; o.x = f2bf(v.x); o.y = f2bf(v.y); o.z = f2bf(v.z); o.w = f2bf(v.w);
        ((ushort4*)d)[i] = o;
    }
}

// ---------------------------------------------------------------------------
// Pack LSTM weights from source row sr = g*H + j into TWO layouts:
//  old (v2 fallback): row j*4+g, k 0..1023 (k<512 ih, else hh), row-major.
//  new (persistent, FRAG-MAJOR): per n-block nb=j>>4 (64 gate-rows = 4 gates
//  x 16 j's), fragment f = kc*8 + xh*4 + g is 1024 contiguous bytes in exact
//  MFMA lane order: ushort idx = nb*65536 + f*512 + (q*16+ln)*8 + e, where
//  lane = q*16+ln holds row g*16+ln, k = xh*512 + kc*32 + q*8 + e.
//  -> a wave's ds_read_b128 is base + f*1024 + lane*16: linear, conflict-free.
// ---------------------------------------------------------------------------
__global__ void k_pack_w(const float* __restrict__ Wih, const float* __restrict__ Whh,
                         const float* __restrict__ bih, const float* __restrict__ bhh,
                         unsigned short* __restrict__ Wold, float* __restrict__ bold,
                         unsigned short* __restrict__ Wnew, float* __restrict__ bnew) {
    int sr = blockIdx.x;              // 0..2047 source row: g*512 + j
    int g = sr >> 9, j = sr & 511;
    int nb = j >> 4, ln = j & 15;
    int np_old = j * 4 + g;
    int t = threadIdx.x;
    int xh = t >> 7;                  // 0: Wih half, 1: Whh half
    int t4 = (t & 127) * 4;           // k offset within half
    const float* src = (xh ? Whh : Wih) + (size_t)sr * H_ + t4;
    float4 v = *(const float4*)src;
    ushort4 o; o.x = f2bf(v.x); o.y = f2bf(v.y); o.z = f2bf(v.z); o.w = f2bf(v.w);
    *(ushort4*)(Wold + (size_t)np_old * 1024 + xh * 512 + t4) = o;
    int kc = t4 >> 5, qq = (t4 >> 3) & 3, e0 = t4 & 7;
    *(ushort4*)(Wnew + (size_t)nb * 65536
                + (size_t)((kc << 3) + (xh << 2) + g) * 512
                + (qq * 16 + ln) * 8 + e0) = o;
    if (t == 0) {
        float bv = bih[sr] + bhh[sr];
        bold[np_old] = bv;
        bnew[nb * 64 + g * 16 + ln] = bv;
    }
}

// ---------------------------------------------------------------------------
// x0relu[j] = relu(b_emb[j] + start . W_emb[j,:]) -> bf16.  Also zeros the
// 8 inter-block barrier counters (runs before the persistent kernel).
// ---------------------------------------------------------------------------
__global__ void k_x0(const float* __restrict__ start, const float* __restrict__ Wemb,
                     const float* __restrict__ bemb, unsigned short* __restrict__ x0,
                     unsigned* __restrict__ bar) {
    if (blockIdx.x == 0 && threadIdx.x < 8) bar[threadIdx.x * 64] = 0u;
    int j = blockIdx.x * 256 + threadIdx.x;
    if (j < H_) {
        float s = bemb[j];
        const float* wp = Wemb + (size_t)j * O_;
        #pragma unroll 4
        for (int o = 0; o < O_; ++o) s += start[o] * wp[o];
        x0[j] = f2bf(fmaxf(s, 0.f));
    }
}

// ---------------------------------------------------------------------------
// g0vec[np] (np = nb*64 + g*16 + ln) = x0 . Wih[row g*512 + nb*16 + ln, :]
// Reads Wnew in frag-major layout (xh = 0 half).
// ---------------------------------------------------------------------------
__global__ void k_g0(const unsigned short* __restrict__ x0,
                     const unsigned short* __restrict__ Wnew,
                     float* __restrict__ g0vec) {
    int np = blockIdx.x;
    int nb = np >> 6, f6 = np & 63;
    int g = f6 >> 4, ln = f6 & 15;
    int l = threadIdx.x;              // 64 threads; k = kc*32 + q*8 + e
    int kc = l >> 2, q = l & 3;
    const unsigned short* wr = Wnew + (size_t)nb * 65536
                             + (size_t)((kc << 3) + g) * 512 + (q * 16 + ln) * 8;
    const unsigned short* xr = x0 + kc * 32 + q * 8;
    float s = 0.f;
    #pragma unroll
    for (int e = 0; e < 8; ++e) s += bf2f(xr[e]) * bf2f(wr[e]);
    #pragma unroll
    for (int d = 32; d > 0; d >>= 1) s += __shfl_down(s, d, 64);
    if (l == 0) g0vec[np] = s;
}

// ---------------------------------------------------------------------------
// fp32 tiled init projection with leaky_relu; writes fp32 and/or bf16.
// ---------------------------------------------------------------------------
__global__ __launch_bounds__(256) void k_proj_act(
    const float* __restrict__ A, const float* __restrict__ W,
    const float* __restrict__ bias, float* __restrict__ outf,
    unsigned short* __restrict__ outbf, int M, int N, int K)
{
    __shared__ __align__(16) float As[16][68];
    __shared__ __align__(16) float Bs[16][68];
    const int tid = threadIdx.x;
    const int tx = tid & 15, ty = tid >> 4;
    const int m0 = blockIdx.y * 64, n0 = blockIdx.x * 64;
    float acc[4][4] = {};
    for (int kt = 0; kt < K; kt += 16) {
        int m = tid >> 2, k4 = (tid & 3) * 4;
        float4 av = *(const float4*)(A + (size_t)(m0 + m) * K + kt + k4);
        As[k4 + 0][m] = av.x; As[k4 + 1][m] = av.y; As[k4 + 2][m] = av.z; As[k4 + 3][m] = av.w;
        float4 bv = *(const float4*)(W + (size_t)(n0 + m) * K + kt + k4);
        Bs[k4 + 0][m] = bv.x; Bs[k4 + 1][m] = bv.y; Bs[k4 + 2][m] = bv.z; Bs[k4 + 3][m] = bv.w;
        __syncthreads();
        #pragma unroll
        for (int kk = 0; kk < 16; ++kk) {
            float4 a = *(const float4*)&As[kk][ty * 4];
            float4 b = *(const float4*)&Bs[kk][tx * 4];
            float aa[4] = {a.x, a.y, a.z, a.w}, bb[4] = {b.x, b.y, b.z, b.w};
            #pragma unroll
            for (int i = 0; i < 4; ++i)
                #pragma unroll
                for (int j = 0; j < 4; ++j) acc[i][j] += aa[i] * bb[j];
        }
        __syncthreads();
    }
    #pragma unroll
    for (int i = 0; i < 4; ++i) {
        int m = m0 + ty * 4 + i;
        #pragma unroll
        for (int j = 0; j < 4; ++j) {
            int n = n0 + tx * 4 + j;
            float v = acc[i][j] + bias[n];
            v = v > 0.f ? v : 0.01f * v;
            if (outf)  outf[(size_t)m * N + n] = v;
            if (outbf) outbf[(size_t)m * N + n] = f2bf(v);
        }
    }
}

// ---------------------------------------------------------------------------
// PERSISTENT LSTM, custom XCD-local barriers.
// 256 blocks (1/CU) x 4 waves; block (mb=b&7, nb=b>>3): 128 rows x 64 gate-
// cols; frag-major weight slice (128 KiB) staged to LDS once (linear copy,
// conflict-free reads: addr = frag*1024 + lane*16). Wave = 32 rows.
// Block reads only h-rows [mb*128,+128), written only by the 32 blocks with
// the same mb (b%8==mb -> same XCD under round-robin) -> 8 independent
// 32-block barriers: monotone counter, threadfence + agent release add,
// acquire spin with s_sleep. grid.sync() (35 us/step in R3) eliminated.
// c lives in 8 VGPRs; gates per-lane (gate-grouped cols); t=0 x-part folded
// into g0vec.
// ---------------------------------------------------------------------------
__global__ __launch_bounds__(256, 1) void k_lstm_persist(
    const unsigned short* __restrict__ h0,
    unsigned short* __restrict__ hist,
    const unsigned short* __restrict__ Wnew,
    const float* __restrict__ bnew,
    const float* __restrict__ c0,
    const float* __restrict__ g0vec,
    float* __restrict__ hT_out,
    float* __restrict__ cT_out,
    unsigned* __restrict__ bar)
{
    __shared__ __align__(16) unsigned short Bs[64 * 1024];   // 128 KiB
    const int tid = threadIdx.x;
    const int lane = tid & 63, wv = tid >> 6;
    const int ln = lane & 15, q = lane >> 4;
    const int b = blockIdx.x;
    const int mb = b & 7, nb = b >> 3;
    const int mw = mb * 128 + wv * 32;

    // ---- stage frag-major weight slice: linear 128 KiB copy ----
    {
        const unsigned short* wsrc = Wnew + (size_t)nb * 65536;
        #pragma unroll
        for (int it = 0; it < 32; ++it) {
            int flat = it * 2048 + tid * 8;
            *(uint4*)&Bs[flat] = *(const uint4*)(wsrc + flat);
        }
    }

    const int j = nb * 16 + ln;
    const float b_i = bnew[nb * 64 + ln],      b_f = bnew[nb * 64 + 16 + ln];
    const float b_g = bnew[nb * 64 + 32 + ln], b_o = bnew[nb * 64 + 48 + ln];
    const float g0_i = g0vec[nb * 64 + ln],      g0_f = g0vec[nb * 64 + 16 + ln];
    const float g0_g = g0vec[nb * 64 + 32 + ln], g0_o = g0vec[nb * 64 + 48 + ln];
    const char* BsL = (const char*)Bs + lane * 16;

    float c_reg[2][4];
    #pragma unroll
    for (int mt = 0; mt < 2; ++mt)
        #pragma unroll
        for (int r = 0; r < 4; ++r)
            c_reg[mt][r] = c0[(size_t)(mw + mt * 16 + q * 4 + r) * H_ + j];

    unsigned* cnt = bar + mb * 64;
    __syncthreads();                                 // Bs ready (block-local)

    for (int t = 0; t < SEQ_; ++t) {
        const unsigned short* hprev = (t == 0) ? h0 : hist + (size_t)(t - 1) * (B_ * H_);
        const unsigned short* a0p = hprev + (size_t)(mw + ln) * H_ + q * 8;
        const unsigned short* a1p = hprev + (size_t)(mw + 16 + ln) * H_ + q * 8;
        f32x4 acc[2][4] = {};

        if (t == 0) {
            // h-only GEMM (x-part is g0vec); frags xh=1
            #pragma unroll
            for (int kc = 0; kc < 16; ++kc) {
                uint4 ah0 = *(const uint4*)(a0p + kc * 32);
                uint4 ah1 = *(const uint4*)(a1p + kc * 32);
                #pragma unroll
                for (int g = 0; g < 4; ++g) {
                    short8 bfh = *(const short8*)(BsL + (kc * 8 + 4 + g) * 1024);
                    acc[0][g] = __builtin_amdgcn_mfma_f32_16x16x32_bf16(*(const short8*)&ah0, bfh, acc[0][g], 0, 0, 0);
                    acc[1][g] = __builtin_amdgcn_mfma_f32_16x16x32_bf16(*(const short8*)&ah1, bfh, acc[1][g], 0, 0, 0);
                }
            }
        } else {
            uint4 ah0 = *(const uint4*)(a0p);
            uint4 ah1 = *(const uint4*)(a1p);
            #pragma unroll
            for (int kc = 0; kc < 16; ++kc) {
                uint4 an0, an1;
                if (kc < 15) {
                    an0 = *(const uint4*)(a0p + (kc + 1) * 32);
                    an1 = *(const uint4*)(a1p + (kc + 1) * 32);
                }
                uint4 ax0 = relu8bf(ah0), ax1 = relu8bf(ah1);
                #pragma unroll
                for (int g = 0; g < 4; ++g) {
                    short8 bfx = *(const short8*)(BsL + (kc * 8 + g) * 1024);
                    short8 bfh = *(const short8*)(BsL + (kc * 8 + 4 + g) * 1024);
                    acc[0][g] = __builtin_amdgcn_mfma_f32_16x16x32_bf16(*(const short8*)&ax0, bfx, acc[0][g], 0, 0, 0);
                    acc[1][g] = __builtin_amdgcn_mfma_f32_16x16x32_bf16(*(const short8*)&ax1, bfx, acc[1][g], 0, 0, 0);
                    acc[0][g] = __builtin_amdgcn_mfma_f32_16x16x32_bf16(*(const short8*)&ah0, bfh, acc[0][g], 0, 0, 0);
                    acc[1][g] = __builtin_amdgcn_mfma_f32_16x16x32_bf16(*(const short8*)&ah1, bfh, acc[1][g], 0, 0, 0);
                }
                if (kc < 15) { ah0 = an0; ah1 = an1; }
            }
        }

        // ---- per-lane gate math + stores ----
        #pragma unroll
        for (int mt = 0; mt < 2; ++mt) {
            #pragma unroll
            for (int r = 0; r < 4; ++r) {
                float iv = acc[mt][0][r] + b_i;
                float fv = acc[mt][1][r] + b_f;
                float gv = acc[mt][2][r] + b_g;
                float ov = acc[mt][3][r] + b_o;
                if (t == 0) { iv += g0_i; fv += g0_f; gv += g0_g; ov += g0_o; }
                float cn = sigmoidf_(fv) * c_reg[mt][r] + sigmoidf_(iv) * tanhf_(gv);
                float hn = sigmoidf_(ov) * tanhf_(cn);
                c_reg[mt][r] = cn;
                int m = mw + mt * 16 + q * 4 + r;
                hist[(size_t)t * (B_ * H_) + (size_t)m * H_ + j] = f2bf(hn);
                if (t == SEQ_ - 1) {
                    hT_out[(size_t)m * H_ + j] = hn;
                    cT_out[(size_t)m * H_ + j] = cn;
                }
            }
        }

        // ---- 32-block (same-mb) barrier ----
        if (t < SEQ_ - 1) {
            __threadfence();                 // this thread's hist stores -> agent visible
            __syncthreads();                 // whole block done storing+fenced
            if (tid == 0) {
                __hip_atomic_fetch_add(cnt, 1u, __ATOMIC_RELEASE, __HIP_MEMORY_SCOPE_AGENT);
                const unsigned tgt = 32u * (unsigned)(t + 1);
                while (__hip_atomic_load(cnt, __ATOMIC_ACQUIRE, __HIP_MEMORY_SCOPE_AGENT) < tgt)
                    __builtin_amdgcn_s_sleep(1);
            }
            __syncthreads();                 // all threads see fresh hist (L1 inv'd by acquire)
        }
    }
}

// ---------------------------------------------------------------------------
// FALLBACK per-step LSTM (round-2 kernel, OLD weight layout) — used only if
// cooperative launch is rejected by the capture/runtime.
// ---------------------------------------------------------------------------
__global__ __launch_bounds__(256, 1) void k_lstm_v2(
    const unsigned short* __restrict__ xsrc, int x_stride,
    const unsigned short* __restrict__ hsrc,
    const unsigned short* __restrict__ Wcat,
    const float* __restrict__ biasp,
    float* __restrict__ c,
    unsigned short* __restrict__ hist_t,
    unsigned short* __restrict__ xrelu_out,
    float* __restrict__ hT_out)
{
    __shared__ __align__(16) float Gt[2][64][132];
    const int tid = threadIdx.x;
    const int lane = tid & 63, w = tid >> 6;
    const int ln = lane & 15, q = lane >> 4;
    const int i_n = w & 1, i_k = w >> 1;
    const int m0 = blockIdx.y * 64;
    const int n0 = blockIdx.x * 128;

    const unsigned short* Ab[4];
    const unsigned short* Bb[4];
    #pragma unroll
    for (int mt = 0; mt < 4; ++mt) {
        int row = m0 + mt * 16 + ln;
        Ab[mt] = (i_k == 0) ? (xsrc + (size_t)row * x_stride + q * 8)
                            : (hsrc + (size_t)row * H_ + q * 8);
    }
    #pragma unroll
    for (int nt = 0; nt < 4; ++nt)
        Bb[nt] = Wcat + (size_t)(n0 + i_n * 64 + nt * 16 + ln) * 1024 + i_k * 512 + q * 8;

    f32x4 acc[4][4] = {};
    uint4 ab[3][4], bb[3][4];

    #pragma unroll
    for (int s = 0; s < 16 + 2; ++s) {
        if (s < 16) {
            const int p = s % 3;
            #pragma unroll
            for (int mt = 0; mt < 4; ++mt)
                ab[p][mt] = *(const uint4*)(Ab[mt] + s * 32);
            #pragma unroll
            for (int nt = 0; nt < 4; ++nt)
                bb[p][nt] = *(const uint4*)(Bb[nt] + s * 32);
        }
        if (s >= 2) {
            const int p = (s - 2) % 3;
            #pragma unroll
            for (int mt = 0; mt < 4; ++mt)
                #pragma unroll
                for (int nt = 0; nt < 4; ++nt)
                    acc[mt][nt] = __builtin_amdgcn_mfma_f32_16x16x32_bf16(
                        *(const short8*)&ab[p][mt], *(const short8*)&bb[p][nt],
                        acc[mt][nt], 0, 0, 0);
        }
    }

    #pragma unroll
    for (int mt = 0; mt < 4; ++mt)
        #pragma unroll
        for (int nt = 0; nt < 4; ++nt)
            #pragma unroll
            for (int r = 0; r < 4; ++r)
                Gt[i_k][mt * 16 + q * 4 + r][i_n * 64 + nt * 16 + ln] = acc[mt][nt][r];
    __syncthreads();

    const int j0 = n0 >> 2;
    #pragma unroll
    for (int l = 0; l < 8; ++l) {
        int idx = l * 256 + tid;
        int m = idx >> 5, jj = idx & 31;
        float4 g0 = *(const float4*)&Gt[0][m][jj * 4];
        float4 g1 = *(const float4*)&Gt[1][m][jj * 4];
        float4 bv = *(const float4*)&biasp[n0 + jj * 4];
        float iv = g0.x + g1.x + bv.x;
        float fv = g0.y + g1.y + bv.y;
        float gv = g0.z + g1.z + bv.z;
        float ov = g0.w + g1.w + bv.w;
        size_t off = (size_t)(m0 + m) * H_ + (j0 + jj);
        float cv = c[off];
        float cn = sigmoidf_(fv) * cv + sigmoidf_(iv) * tanhf_(gv);
        float hn = sigmoidf_(ov) * tanhf_(cn);
        c[off] = cn;
        hist_t[off] = f2bf(hn);
        xrelu_out[off] = f2bf(fmaxf(hn, 0.f));
        if (hT_out) hT_out[off] = hn;
    }
}

// ---------------------------------------------------------------------------
// Output projection with register-prefetch. M=102400, N=128, K=512.
// ---------------------------------------------------------------------------
__global__ __launch_bounds__(256) void k_outproj_mfma(
    const unsigned short* __restrict__ hist,
    const unsigned short* __restrict__ Wo,
    const float* __restrict__ bo,
    float* __restrict__ out)
{
    __shared__ __align__(16) unsigned short As[64 * RS];
    __shared__ __align__(16) unsigned short Bs[64 * RS];
    const int tid = threadIdx.x;
    const int lane = tid & 63, w = tid >> 6;
    const int q = lane >> 4, ln = lane & 15;
    const int wrow = w & 1, wcol = w >> 1;
    const int m0 = blockIdx.y * 64, n0 = blockIdx.x * 64;
    const int r0 = tid >> 3, cc = (tid & 7) * 8;
    f32x4 acc[2][2] = {};
    uint4 a0 = *(const uint4*)(hist + (size_t)(m0 + r0) * H_ + cc);
    uint4 a1 = *(const uint4*)(hist + (size_t)(m0 + r0 + 32) * H_ + cc);
    uint4 b0 = *(const uint4*)(Wo + (size_t)(n0 + r0) * H_ + cc);
    uint4 b1 = *(const uint4*)(Wo + (size_t)(n0 + r0 + 32) * H_ + cc);
    for (int it = 0; it < 8; ++it) {
        __syncthreads();
        *(uint4*)&As[r0 * RS + cc] = a0;
        *(uint4*)&As[(r0 + 32) * RS + cc] = a1;
        *(uint4*)&Bs[r0 * RS + cc] = b0;
        *(uint4*)&Bs[(r0 + 32) * RS + cc] = b1;
        __syncthreads();
        if (it < 7) {
            int kt = (it + 1) * 64;
            a0 = *(const uint4*)(hist + (size_t)(m0 + r0) * H_ + kt + cc);
            a1 = *(const uint4*)(hist + (size_t)(m0 + r0 + 32) * H_ + kt + cc);
            b0 = *(const uint4*)(Wo + (size_t)(n0 + r0) * H_ + kt + cc);
            b1 = *(const uint4*)(Wo + (size_t)(n0 + r0 + 32) * H_ + kt + cc);
        }
        #pragma unroll
        for (int kh = 0; kh < 2; ++kh) {
            short8 af0 = *(const short8*)&As[(wrow * 32 + ln) * RS + kh * 32 + q * 8];
            short8 af1 = *(const short8*)&As[(wrow * 32 + 16 + ln) * RS + kh * 32 + q * 8];
            short8 bf0 = *(const short8*)&Bs[(wcol * 32 + ln) * RS + kh * 32 + q * 8];
            short8 bf1 = *(const short8*)&Bs[(wcol * 32 + 16 + ln) * RS + kh * 32 + q * 8];
            acc[0][0] = __builtin_amdgcn_mfma_f32_16x16x32_bf16(af0, bf0, acc[0][0], 0, 0, 0);
            acc[0][1] = __builtin_amdgcn_mfma_f32_16x16x32_bf16(af0, bf1, acc[0][1], 0, 0, 0);
            acc[1][0] = __builtin_amdgcn_mfma_f32_16x16x32_bf16(af1, bf0, acc[1][0], 0, 0, 0);
            acc[1][1] = __builtin_amdgcn_mfma_f32_16x16x32_bf16(af1, bf1, acc[1][1], 0, 0, 0);
        }
    }
    #pragma unroll
    for (int mt = 0; mt < 2; ++mt)
        #pragma unroll
        for (int nt = 0; nt < 2; ++nt) {
            int n = n0 + wcol * 32 + nt * 16 + ln;
            float bv = bo[n];
            #pragma unroll
            for (int r = 0; r < 4; ++r) {
                int row = m0 + wrow * 32 + mt * 16 + q * 4 + r;
                int t = row >> 10, b = row & 1023;
                out[(size_t)b * (SEQ_ * O_) + t * O_ + n] = acc[mt][nt][r] + bv;
            }
        }
}

// ---------------------------------------------------------------------------
// num head, fused fp32->bf16 A staging (once per block), B chunks from L2.
// ---------------------------------------------------------------------------
__global__ __launch_bounds__(256) void k_num_mfma(
    const float* __restrict__ enc,
    const unsigned short* __restrict__ Wseq,
    const float* __restrict__ bseq,
    const float* __restrict__ w2,
    const float* __restrict__ b2,
    float* __restrict__ out)
{
    __shared__ __align__(16) unsigned short As[64 * AR];
    __shared__ __align__(16) unsigned short Bs[64 * AR];
    const int tid = threadIdx.x;
    const int lane = tid & 63, w = tid >> 6;
    const int q = lane >> 4, ln = lane & 15;
    const int wrow = w & 1, wcol = w >> 1;
    const int m0 = blockIdx.x * 64;

    {
        const float* base = enc + (size_t)m0 * L_;
        #pragma unroll 4
        for (int it = 0; it < 16; ++it) {
            int flat = it * 1024 + tid * 4;
            int row = flat >> 8, col = flat & 255;
            float4 v = *(const float4*)(base + flat);
            ushort4 o; o.x = f2bf(v.x); o.y = f2bf(v.y); o.z = f2bf(v.z); o.w = f2bf(v.w);
            *(ushort4*)&As[row * AR + col] = o;
        }
    }
    float partial[2][4] = {};
    for (int nc = 0; nc < 8; ++nc) {
        __syncthreads();
        {
            const unsigned short* bb = Wseq + (size_t)nc * 64 * L_;
            #pragma unroll
            for (int it = 0; it < 8; ++it) {
                int flat = it * 2048 + tid * 8;
                int row = flat >> 8, col = flat & 255;
                *(uint4*)&Bs[row * AR + col] = *(const uint4*)(bb + flat);
            }
        }
        __syncthreads();
        f32x4 acc[2][2] = {};
        #pragma unroll
        for (int kt = 0; kt < 8; ++kt) {
            short8 af0 = *(const short8*)&As[(wrow * 32 + ln) * AR + kt * 32 + q * 8];
            short8 af1 = *(const short8*)&As[(wrow * 32 + 16 + ln) * AR + kt * 32 + q * 8];
            short8 bf0 = *(const short8*)&Bs[(wcol * 32 + ln) * AR + kt * 32 + q * 8];
            short8 bf1 = *(const short8*)&Bs[(wcol * 32 + 16 + ln) * AR + kt * 32 + q * 8];
            acc[0][0] = __builtin_amdgcn_mfma_f32_16x16x32_bf16(af0, bf0, acc[0][0], 0, 0, 0);
            acc[0][1] = __builtin_amdgcn_mfma_f32_16x16x32_bf16(af0, bf1, acc[0][1], 0, 0, 0);
            acc[1][0] = __builtin_amdgcn_mfma_f32_16x16x32_bf16(af1, bf0, acc[1][0], 0, 0, 0);
            acc[1][1] = __builtin_amdgcn_mfma_f32_16x16x32_bf16(af1, bf1, acc[1][1], 0, 0, 0);
        }
        #pragma unroll
        for (int nt = 0; nt < 2; ++nt) {
            int n = nc * 64 + wcol * 32 + nt * 16 + ln;
            float bs = bseq[n], wv = w2[n];
            #pragma unroll
            for (int mt = 0; mt < 2; ++mt)
                #pragma unroll
                for (int r = 0; r < 4; ++r) {
                    float v = acc[mt][nt][r] + bs;
                    v = v > 0.f ? v : 0.01f * v;
                    partial[mt][r] += v * wv;
                }
        }
    }
    __syncthreads();
    float* R = (float*)As;
    #pragma unroll
    for (int mt = 0; mt < 2; ++mt)
        #pragma unroll
        for (int r = 0; r < 4; ++r)
            R[(wrow * 32 + mt * 16 + q * 4 + r) * 33 + wcol * 16 + ln] = partial[mt][r];
    __syncthreads();
    if (tid < 64) {
        float s = b2[0];
        #pragma unroll 8
        for (int k2 = 0; k2 < 32; ++k2) s += R[tid * 33 + k2];
        out[m0 + tid] = fmaxf(s, 0.f);
    }
}

// ---------------------------------------------------------------------------
extern "C" void kernel_launch(void* const* d_in, const int* in_sizes, int n_in,
                              void* d_out, int out_size, void* d_ws, size_t ws_size,
                              hipStream_t stream) {
    const float* enc_out = (const float*)d_in[0];
    const float* enc_hid = (const float*)d_in[1];
    const float* start   = (const float*)d_in[2];
    const float* W_l2h   = (const float*)d_in[3];
    const float* b_l2h   = (const float*)d_in[4];
    const float* W_l2h2  = (const float*)d_in[5];
    const float* b_l2h2  = (const float*)d_in[6];
    const float* W_emb   = (const float*)d_in[7];
    const float* b_emb   = (const float*)d_in[8];
    const float* W_ih    = (const float*)d_in[9];
    const float* W_hh    = (const float*)d_in[10];
    const float* b_ih    = (const float*)d_in[11];
    const float* b_hh    = (const float*)d_in[12];
    const float* W_out_p = (const float*)d_in[13];
    const float* b_out_p = (const float*)d_in[14];
    const float* W_seq   = (const float*)d_in[15];
    const float* b_seq   = (const float*)d_in[16];
    const float* W_seq2  = (const float*)d_in[17];
    const float* b_seq2  = (const float*)d_in[18];

    float* out = (float*)d_out;
    float* out_dec = out;                                   // [B, SEQ, O]
    float* out_hT  = out + (size_t)B_ * SEQ_ * O_;          // [1, B, H]
    float* out_cT  = out_hT + (size_t)B_ * H_;              // [1, B, H]
    float* out_num = out_cT + (size_t)B_ * H_;              // [B, TE, 1]

    char* w = (char*)d_ws;
    unsigned short* hist = (unsigned short*)w;    w += (size_t)SEQ_ * B_ * H_ * 2;
    float* cbuf = (float*)w;                      w += (size_t)B_ * H_ * 4;
    unsigned short* h0_bf = (unsigned short*)w;   w += (size_t)B_ * H_ * 2;
    unsigned short* Wold = (unsigned short*)w;    w += (size_t)2048 * 1024 * 2;
    unsigned short* Wnew = (unsigned short*)w;    w += (size_t)2048 * 1024 * 2;
    float* bold = (float*)w;                      w += 2048 * 4;
    float* bnew = (float*)w;                      w += 2048 * 4;
    float* g0vec = (float*)w;                     w += 2048 * 4;
    unsigned* bar = (unsigned*)w;                 w += 8 * 64 * 4;
    unsigned short* Wout_bf = (unsigned short*)w; w += (size_t)O_ * H_ * 2;
    unsigned short* Wseq_bf = (unsigned short*)w; w += (size_t)H_ * L_ * 2;
    unsigned short* x0_bf = (unsigned short*)w;   w += 4096;
    unsigned short* xr0 = (unsigned short*)w;     w += (size_t)B_ * H_ * 2;
    unsigned short* xr1 = (unsigned short*)w;     w += (size_t)B_ * H_ * 2;

    // ---- weight prep ----
    k_pack_w<<<dim3(2048), dim3(256), 0, stream>>>(W_ih, W_hh, b_ih, b_hh,
                                                   Wold, bold, Wnew, bnew);
    k_cvt<<<dim3((O_ * H_ / 4 + 255) / 256), dim3(256), 0, stream>>>(W_out_p, Wout_bf, O_ * H_ / 4);
    k_cvt<<<dim3((H_ * L_ / 4 + 255) / 256), dim3(256), 0, stream>>>(W_seq, Wseq_bf, H_ * L_ / 4);
    k_x0<<<dim3(2), dim3(256), 0, stream>>>(start, W_emb, b_emb, x0_bf, bar);
    k_g0<<<dim3(2048), dim3(64), 0, stream>>>(x0_bf, Wnew, g0vec);

    // ---- init h0 (bf16), c0 (fp32) ----
    dim3 g_init(H_ / 64, B_ / 64);
    k_proj_act<<<g_init, dim3(256), 0, stream>>>(enc_hid, W_l2h,  b_l2h,  nullptr, h0_bf, B_, H_, L_);
    k_proj_act<<<g_init, dim3(256), 0, stream>>>(enc_hid, W_l2h2, b_l2h2, cbuf, nullptr, B_, H_, L_);

    // ---- 100 LSTM steps: persistent kernel, custom XCD-local barriers ----
    {
        void* kargs[] = {
            (void*)&h0_bf, (void*)&hist, (void*)&Wnew, (void*)&bnew,
            (void*)&cbuf, (void*)&g0vec, (void*)&out_hT, (void*)&out_cT, (void*)&bar
        };
        hipError_t ce = hipLaunchCooperativeKernel((const void*)k_lstm_persist,
                                                   dim3(256), dim3(256), kargs, 0, stream);
        if (ce != hipSuccess) {
            // fallback: per-step launches (round-2 path, old weight layout)
            dim3 g_lstm(2048 / 128, B_ / 64);
            for (int t = 0; t < SEQ_; ++t) {
                const unsigned short* hprev = (t == 0) ? h0_bf : hist + (size_t)(t - 1) * B_ * H_;
                const unsigned short* xs = (t == 0) ? x0_bf : ((t & 1) ? xr1 : xr0);
                int xstr = (t == 0) ? 0 : H_;
                unsigned short* xout = (t & 1) ? xr0 : xr1;
                float* hT = (t == SEQ_ - 1) ? out_hT : nullptr;
                k_lstm_v2<<<g_lstm, dim3(256), 0, stream>>>(xs, xstr, hprev, Wold, bold, cbuf,
                                                            hist + (size_t)t * B_ * H_, xout, hT);
            }
            hipMemcpyAsync(out_cT, cbuf, (size_t)B_ * H_ * 4, hipMemcpyDeviceToDevice, stream);
        }
    }

    // ---- batched output projection ----
    k_outproj_mfma<<<dim3(O_ / 64, (SEQ_ * B_) / 64), dim3(256), 0, stream>>>(hist, Wout_bf,
                                                                              b_out_p, out_dec);
    // ---- num head ----
    k_num_mfma<<<dim3((B_ * TE_) / 64), dim3(256), 0, stream>>>(enc_out, Wseq_bf, b_seq,
                                                                W_seq2, b_seq2, out_num);
}

// Round 5
// 2054.659 us; speedup vs baseline: 2.0115x; 2.0115x over previous
//
#include <hip/hip_runtime.h>
#include <hip/hip_bf16.h>

#define B_   1024
#define H_   512
#define L_   256
#define O_   128
#define SEQ_ 100
#define TE_  200
#define RS   72    // LDS row stride (ushorts) for 64-wide bf16 tiles (+8 pad)
#define AR   264   // LDS row stride (ushorts) for 256-wide bf16 tiles (+8 pad)

typedef __attribute__((ext_vector_type(8))) short short8;
typedef __attribute__((ext_vector_type(4))) float f32x4;

union U16 { unsigned long long u[2]; uint4 v; short8 s; };

__device__ __forceinline__ float sigmoidf_(float x) { return 1.f / (1.f + __expf(-x)); }
__device__ __forceinline__ float tanhf_(float x) { return 1.f - 2.f / (__expf(2.f * x) + 1.f); }
__device__ __forceinline__ unsigned short f2bf(float x) {
    union { float f; unsigned u; } c; c.f = x;
    unsigned r = c.u + 0x7fffu + ((c.u >> 16) & 1u);   // RNE
    return (unsigned short)(r >> 16);
}
__device__ __forceinline__ float bf2f(unsigned short u) {
    union { unsigned u; float f; } c; c.u = (unsigned)u << 16; return c.f;
}
__device__ __forceinline__ unsigned relu2bf(unsigned x) {
    unsigned hi = x & 0xFFFF0000u, lo = x & 0x0000FFFFu;
    if (x & 0x80000000u) hi = 0u;
    if (x & 0x00008000u) lo = 0u;
    return hi | lo;
}
__device__ __forceinline__ uint4 relu8bf(uint4 v) {
    v.x = relu2bf(v.x); v.y = relu2bf(v.y); v.z = relu2bf(v.z); v.w = relu2bf(v.w);
    return v;
}

// ---------------------------------------------------------------------------
// fp32 -> bf16 convert (n4 = count/4) — used for small weights only
// ---------------------------------------------------------------------------
__global__ void k_cvt(const float* __restrict__ s, unsigned short* __restrict__ d, int n4) {
    int i = blockIdx.x * 256 + threadIdx.x;
    if (i < n4) {
        float4 v = ((const float4*)s)[i];
        ushort4 o; o.x = f2bf(v.x); o.y = f2bf(v.y); o.z = f2bf(v.z); o.w = f2bf(v.w);
        ((ushort4*)d)[i] = o;
    }
}

// ---------------------------------------------------------------------------
// Pack LSTM weights from source row sr = g*H + j into TWO layouts:
//  old (v2 fallback): row j*4+g, k 0..1023 (k<512 ih, else hh), row-major.
//  new (persistent, FRAG-MAJOR): per n-block nb=j>>4, fragment f = kc*8+xh*4+g
//  is 1024 contiguous bytes in exact MFMA lane order (ds_read conflict-free).
// ---------------------------------------------------------------------------
__global__ void k_pack_w(const float* __restrict__ Wih, const float* __restrict__ Whh,
                         const float* __restrict__ bih, const float* __restrict__ bhh,
                         unsigned short* __restrict__ Wold, float* __restrict__ bold,
                         unsigned short* __restrict__ Wnew, float* __restrict__ bnew) {
    int sr = blockIdx.x;              // 0..2047 source row: g*512 + j
    int g = sr >> 9, j = sr & 511;
    int nb = j >> 4, ln = j & 15;
    int np_old = j * 4 + g;
    int t = threadIdx.x;
    int xh = t >> 7;                  // 0: Wih half, 1: Whh half
    int t4 = (t & 127) * 4;           // k offset within half
    const float* src = (xh ? Whh : Wih) + (size_t)sr * H_ + t4;
    float4 v = *(const float4*)src;
    ushort4 o; o.x = f2bf(v.x); o.y = f2bf(v.y); o.z = f2bf(v.z); o.w = f2bf(v.w);
    *(ushort4*)(Wold + (size_t)np_old * 1024 + xh * 512 + t4) = o;
    int kc = t4 >> 5, qq = (t4 >> 3) & 3, e0 = t4 & 7;
    *(ushort4*)(Wnew + (size_t)nb * 65536
                + (size_t)((kc << 3) + (xh << 2) + g) * 512
                + (qq * 16 + ln) * 8 + e0) = o;
    if (t == 0) {
        float bv = bih[sr] + bhh[sr];
        bold[np_old] = bv;
        bnew[nb * 64 + g * 16 + ln] = bv;
    }
}

// ---------------------------------------------------------------------------
// x0relu + zero the 8 inter-block barrier counters.
// ---------------------------------------------------------------------------
__global__ void k_x0(const float* __restrict__ start, const float* __restrict__ Wemb,
                     const float* __restrict__ bemb, unsigned short* __restrict__ x0,
                     unsigned* __restrict__ bar) {
    if (blockIdx.x == 0 && threadIdx.x < 8) bar[threadIdx.x * 64] = 0u;
    int j = blockIdx.x * 256 + threadIdx.x;
    if (j < H_) {
        float s = bemb[j];
        const float* wp = Wemb + (size_t)j * O_;
        #pragma unroll 4
        for (int o = 0; o < O_; ++o) s += start[o] * wp[o];
        x0[j] = f2bf(fmaxf(s, 0.f));
    }
}

// ---------------------------------------------------------------------------
// g0vec[np] (np = nb*64 + g*16 + ln) = x0 . Wih row (frag-major read).
// ---------------------------------------------------------------------------
__global__ void k_g0(const unsigned short* __restrict__ x0,
                     const unsigned short* __restrict__ Wnew,
                     float* __restrict__ g0vec) {
    int np = blockIdx.x;
    int nb = np >> 6, f6 = np & 63;
    int g = f6 >> 4, ln = f6 & 15;
    int l = threadIdx.x;              // 64 threads; k = kc*32 + q*8 + e
    int kc = l >> 2, q = l & 3;
    const unsigned short* wr = Wnew + (size_t)nb * 65536
                             + (size_t)((kc << 3) + g) * 512 + (q * 16 + ln) * 8;
    const unsigned short* xr = x0 + kc * 32 + q * 8;
    float s = 0.f;
    #pragma unroll
    for (int e = 0; e < 8; ++e) s += bf2f(xr[e]) * bf2f(wr[e]);
    #pragma unroll
    for (int d = 32; d > 0; d >>= 1) s += __shfl_down(s, d, 64);
    if (l == 0) g0vec[np] = s;
}

// ---------------------------------------------------------------------------
// fp32 tiled init projection with leaky_relu; writes fp32 and/or bf16.
// ---------------------------------------------------------------------------
__global__ __launch_bounds__(256) void k_proj_act(
    const float* __restrict__ A, const float* __restrict__ W,
    const float* __restrict__ bias, float* __restrict__ outf,
    unsigned short* __restrict__ outbf, int M, int N, int K)
{
    __shared__ __align__(16) float As[16][68];
    __shared__ __align__(16) float Bs[16][68];
    const int tid = threadIdx.x;
    const int tx = tid & 15, ty = tid >> 4;
    const int m0 = blockIdx.y * 64, n0 = blockIdx.x * 64;
    float acc[4][4] = {};
    for (int kt = 0; kt < K; kt += 16) {
        int m = tid >> 2, k4 = (tid & 3) * 4;
        float4 av = *(const float4*)(A + (size_t)(m0 + m) * K + kt + k4);
        As[k4 + 0][m] = av.x; As[k4 + 1][m] = av.y; As[k4 + 2][m] = av.z; As[k4 + 3][m] = av.w;
        float4 bv = *(const float4*)(W + (size_t)(n0 + m) * K + kt + k4);
        Bs[k4 + 0][m] = bv.x; Bs[k4 + 1][m] = bv.y; Bs[k4 + 2][m] = bv.z; Bs[k4 + 3][m] = bv.w;
        __syncthreads();
        #pragma unroll
        for (int kk = 0; kk < 16; ++kk) {
            float4 a = *(const float4*)&As[kk][ty * 4];
            float4 b = *(const float4*)&Bs[kk][tx * 4];
            float aa[4] = {a.x, a.y, a.z, a.w}, bb[4] = {b.x, b.y, b.z, b.w};
            #pragma unroll
            for (int i = 0; i < 4; ++i)
                #pragma unroll
                for (int j = 0; j < 4; ++j) acc[i][j] += aa[i] * bb[j];
        }
        __syncthreads();
    }
    #pragma unroll
    for (int i = 0; i < 4; ++i) {
        int m = m0 + ty * 4 + i;
        #pragma unroll
        for (int j = 0; j < 4; ++j) {
            int n = n0 + tx * 4 + j;
            float v = acc[i][j] + bias[n];
            v = v > 0.f ? v : 0.01f * v;
            if (outf)  outf[(size_t)m * N + n] = v;
            if (outbf) outbf[(size_t)m * N + n] = f2bf(v);
        }
    }
}

// ---------------------------------------------------------------------------
// PERSISTENT LSTM v3: cache-maintenance-free synchronization.
// R4 lesson: acquire/release agent-scope fences (both grid.sync and custom
// barrier) force L2 wb/inv — polling with ACQUIRE = continuous L2-invalidate
// storm on all 256 CUs (FETCH_SIZE showed hprev missing L2 every step).
// v3: (1) hist stores write THROUGH to LLC (global_store_short sc0 sc1);
//     (2) s_waitcnt vmcnt(0) before a RELAXED counter add (data at coherence
//         point before flag rises — no release fence);
//     (3) polls are RELAXED loads + s_sleep (no per-poll invalidate);
//     (4) hprev loads are RELAXED SYSTEM-scope 8B atomic loads (bypass L1+L2,
//         read LLC) — immune to stale caches under ANY XCD placement (G16),
//         zero cache maintenance. All 64 loads issued upfront, drained once.
// ---------------------------------------------------------------------------
__global__ __launch_bounds__(256, 1) void k_lstm_persist(
    const unsigned short* __restrict__ h0,
    unsigned short* __restrict__ hist,
    const unsigned short* __restrict__ Wnew,
    const float* __restrict__ bnew,
    const float* __restrict__ c0,
    const float* __restrict__ g0vec,
    float* __restrict__ hT_out,
    float* __restrict__ cT_out,
    unsigned* __restrict__ bar)
{
    __shared__ __align__(16) unsigned short Bs[64 * 1024];   // 128 KiB
    const int tid = threadIdx.x;
    const int lane = tid & 63, wv = tid >> 6;
    const int ln = lane & 15, q = lane >> 4;
    const int b = blockIdx.x;
    const int mb = b & 7, nb = b >> 3;
    const int mw = mb * 128 + wv * 32;

    // ---- stage frag-major weight slice: linear 128 KiB copy ----
    {
        const unsigned short* wsrc = Wnew + (size_t)nb * 65536;
        #pragma unroll
        for (int it = 0; it < 32; ++it) {
            int flat = it * 2048 + tid * 8;
            *(uint4*)&Bs[flat] = *(const uint4*)(wsrc + flat);
        }
    }

    const int j = nb * 16 + ln;
    const float b_i = bnew[nb * 64 + ln],      b_f = bnew[nb * 64 + 16 + ln];
    const float b_g = bnew[nb * 64 + 32 + ln], b_o = bnew[nb * 64 + 48 + ln];
    const float g0_i = g0vec[nb * 64 + ln],      g0_f = g0vec[nb * 64 + 16 + ln];
    const float g0_g = g0vec[nb * 64 + 32 + ln], g0_o = g0vec[nb * 64 + 48 + ln];
    const char* BsL = (const char*)Bs + lane * 16;

    float c_reg[2][4];
    #pragma unroll
    for (int mt = 0; mt < 2; ++mt)
        #pragma unroll
        for (int r = 0; r < 4; ++r)
            c_reg[mt][r] = c0[(size_t)(mw + mt * 16 + q * 4 + r) * H_ + j];

    unsigned* cnt = bar + mb * 64;
    __syncthreads();                                 // Bs ready (block-local)

    for (int t = 0; t < SEQ_; ++t) {
        const unsigned short* hprev = (t == 0) ? h0 : hist + (size_t)(t - 1) * (B_ * H_);
        const unsigned short* a0p = hprev + (size_t)(mw + ln) * H_ + q * 8;
        const unsigned short* a1p = hprev + (size_t)(mw + 16 + ln) * H_ + q * 8;

        // ---- issue ALL h-loads for this step (LLC-direct, relaxed) ----
        unsigned long long hl[16][2][2];
        #pragma unroll
        for (int kc = 0; kc < 16; ++kc) {
            hl[kc][0][0] = __hip_atomic_load((const unsigned long long*)(a0p + kc * 32),
                                             __ATOMIC_RELAXED, __HIP_MEMORY_SCOPE_SYSTEM);
            hl[kc][0][1] = __hip_atomic_load((const unsigned long long*)(a0p + kc * 32 + 4),
                                             __ATOMIC_RELAXED, __HIP_MEMORY_SCOPE_SYSTEM);
            hl[kc][1][0] = __hip_atomic_load((const unsigned long long*)(a1p + kc * 32),
                                             __ATOMIC_RELAXED, __HIP_MEMORY_SCOPE_SYSTEM);
            hl[kc][1][1] = __hip_atomic_load((const unsigned long long*)(a1p + kc * 32 + 4),
                                             __ATOMIC_RELAXED, __HIP_MEMORY_SCOPE_SYSTEM);
        }

        f32x4 acc[2][4] = {};
        if (t == 0) {
            // h-only GEMM (x-part folded into g0vec); frags xh=1
            #pragma unroll
            for (int kc = 0; kc < 16; ++kc) {
                U16 A0, A1;
                A0.u[0] = hl[kc][0][0]; A0.u[1] = hl[kc][0][1];
                A1.u[0] = hl[kc][1][0]; A1.u[1] = hl[kc][1][1];
                #pragma unroll
                for (int g = 0; g < 4; ++g) {
                    short8 bfh = *(const short8*)(BsL + (kc * 8 + 4 + g) * 1024);
                    acc[0][g] = __builtin_amdgcn_mfma_f32_16x16x32_bf16(A0.s, bfh, acc[0][g], 0, 0, 0);
                    acc[1][g] = __builtin_amdgcn_mfma_f32_16x16x32_bf16(A1.s, bfh, acc[1][g], 0, 0, 0);
                }
            }
        } else {
            #pragma unroll
            for (int kc = 0; kc < 16; ++kc) {
                U16 A0, A1;
                A0.u[0] = hl[kc][0][0]; A0.u[1] = hl[kc][0][1];
                A1.u[0] = hl[kc][1][0]; A1.u[1] = hl[kc][1][1];
                U16 X0, X1;
                X0.v = relu8bf(A0.v);
                X1.v = relu8bf(A1.v);
                #pragma unroll
                for (int g = 0; g < 4; ++g) {
                    short8 bfx = *(const short8*)(BsL + (kc * 8 + g) * 1024);
                    short8 bfh = *(const short8*)(BsL + (kc * 8 + 4 + g) * 1024);
                    acc[0][g] = __builtin_amdgcn_mfma_f32_16x16x32_bf16(X0.s, bfx, acc[0][g], 0, 0, 0);
                    acc[1][g] = __builtin_amdgcn_mfma_f32_16x16x32_bf16(X1.s, bfx, acc[1][g], 0, 0, 0);
                    acc[0][g] = __builtin_amdgcn_mfma_f32_16x16x32_bf16(A0.s, bfh, acc[0][g], 0, 0, 0);
                    acc[1][g] = __builtin_amdgcn_mfma_f32_16x16x32_bf16(A1.s, bfh, acc[1][g], 0, 0, 0);
                }
            }
        }

        // ---- per-lane gate math + write-through hist stores ----
        #pragma unroll
        for (int mt = 0; mt < 2; ++mt) {
            #pragma unroll
            for (int r = 0; r < 4; ++r) {
                float iv = acc[mt][0][r] + b_i;
                float fv = acc[mt][1][r] + b_f;
                float gv = acc[mt][2][r] + b_g;
                float ov = acc[mt][3][r] + b_o;
                if (t == 0) { iv += g0_i; fv += g0_f; gv += g0_g; ov += g0_o; }
                float cn = sigmoidf_(fv) * c_reg[mt][r] + sigmoidf_(iv) * tanhf_(gv);
                float hn = sigmoidf_(ov) * tanhf_(cn);
                c_reg[mt][r] = cn;
                int m = mw + mt * 16 + q * 4 + r;
                unsigned short* hp = hist + (size_t)t * (B_ * H_) + (size_t)m * H_ + j;
                unsigned hv = (unsigned)f2bf(hn);
                asm volatile("global_store_short %0, %1, off sc0 sc1"
                             :: "v"(hp), "v"(hv) : "memory");
                if (t == SEQ_ - 1) {
                    hT_out[(size_t)m * H_ + j] = hn;
                    cT_out[(size_t)m * H_ + j] = cn;
                }
            }
        }

        // ---- relaxed 32-block (same-mb) barrier, no cache maintenance ----
        if (t < SEQ_ - 1) {
            asm volatile("s_waitcnt vmcnt(0)" ::: "memory");   // stores at LLC
            __syncthreads();
            if (tid == 0) {
                __hip_atomic_fetch_add(cnt, 1u, __ATOMIC_RELAXED, __HIP_MEMORY_SCOPE_SYSTEM);
                const unsigned tgt = 32u * (unsigned)(t + 1);
                while (__hip_atomic_load(cnt, __ATOMIC_RELAXED, __HIP_MEMORY_SCOPE_SYSTEM) < tgt)
                    __builtin_amdgcn_s_sleep(2);
            }
            __syncthreads();
        }
    }
}

// ---------------------------------------------------------------------------
// FALLBACK per-step LSTM (round-2 kernel, OLD weight layout) — used only if
// cooperative launch is rejected by the capture/runtime.
// ---------------------------------------------------------------------------
__global__ __launch_bounds__(256, 1) void k_lstm_v2(
    const unsigned short* __restrict__ xsrc, int x_stride,
    const unsigned short* __restrict__ hsrc,
    const unsigned short* __restrict__ Wcat,
    const float* __restrict__ biasp,
    float* __restrict__ c,
    unsigned short* __restrict__ hist_t,
    unsigned short* __restrict__ xrelu_out,
    float* __restrict__ hT_out)
{
    __shared__ __align__(16) float Gt[2][64][132];
    const int tid = threadIdx.x;
    const int lane = tid & 63, w = tid >> 6;
    const int ln = lane & 15, q = lane >> 4;
    const int i_n = w & 1, i_k = w >> 1;
    const int m0 = blockIdx.y * 64;
    const int n0 = blockIdx.x * 128;

    const unsigned short* Ab[4];
    const unsigned short* Bb[4];
    #pragma unroll
    for (int mt = 0; mt < 4; ++mt) {
        int row = m0 + mt * 16 + ln;
        Ab[mt] = (i_k == 0) ? (xsrc + (size_t)row * x_stride + q * 8)
                            : (hsrc + (size_t)row * H_ + q * 8);
    }
    #pragma unroll
    for (int nt = 0; nt < 4; ++nt)
        Bb[nt] = Wcat + (size_t)(n0 + i_n * 64 + nt * 16 + ln) * 1024 + i_k * 512 + q * 8;

    f32x4 acc[4][4] = {};
    uint4 ab[3][4], bb[3][4];

    #pragma unroll
    for (int s = 0; s < 16 + 2; ++s) {
        if (s < 16) {
            const int p = s % 3;
            #pragma unroll
            for (int mt = 0; mt < 4; ++mt)
                ab[p][mt] = *(const uint4*)(Ab[mt] + s * 32);
            #pragma unroll
            for (int nt = 0; nt < 4; ++nt)
                bb[p][nt] = *(const uint4*)(Bb[nt] + s * 32);
        }
        if (s >= 2) {
            const int p = (s - 2) % 3;
            #pragma unroll
            for (int mt = 0; mt < 4; ++mt)
                #pragma unroll
                for (int nt = 0; nt < 4; ++nt)
                    acc[mt][nt] = __builtin_amdgcn_mfma_f32_16x16x32_bf16(
                        *(const short8*)&ab[p][mt], *(const short8*)&bb[p][nt],
                        acc[mt][nt], 0, 0, 0);
        }
    }

    #pragma unroll
    for (int mt = 0; mt < 4; ++mt)
        #pragma unroll
        for (int nt = 0; nt < 4; ++nt)
            #pragma unroll
            for (int r = 0; r < 4; ++r)
                Gt[i_k][mt * 16 + q * 4 + r][i_n * 64 + nt * 16 + ln] = acc[mt][nt][r];
    __syncthreads();

    const int j0 = n0 >> 2;
    #pragma unroll
    for (int l = 0; l < 8; ++l) {
        int idx = l * 256 + tid;
        int m = idx >> 5, jj = idx & 31;
        float4 g0 = *(const float4*)&Gt[0][m][jj * 4];
        float4 g1 = *(const float4*)&Gt[1][m][jj * 4];
        float4 bv = *(const float4*)&biasp[n0 + jj * 4];
        float iv = g0.x + g1.x + bv.x;
        float fv = g0.y + g1.y + bv.y;
        float gv = g0.z + g1.z + bv.z;
        float ov = g0.w + g1.w + bv.w;
        size_t off = (size_t)(m0 + m) * H_ + (j0 + jj);
        float cv = c[off];
        float cn = sigmoidf_(fv) * cv + sigmoidf_(iv) * tanhf_(gv);
        float hn = sigmoidf_(ov) * tanhf_(cn);
        c[off] = cn;
        hist_t[off] = f2bf(hn);
        xrelu_out[off] = f2bf(fmaxf(hn, 0.f));
        if (hT_out) hT_out[off] = hn;
    }
}

// ---------------------------------------------------------------------------
// Output projection with register-prefetch. M=102400, N=128, K=512.
// ---------------------------------------------------------------------------
__global__ __launch_bounds__(256) void k_outproj_mfma(
    const unsigned short* __restrict__ hist,
    const unsigned short* __restrict__ Wo,
    const float* __restrict__ bo,
    float* __restrict__ out)
{
    __shared__ __align__(16) unsigned short As[64 * RS];
    __shared__ __align__(16) unsigned short Bs[64 * RS];
    const int tid = threadIdx.x;
    const int lane = tid & 63, w = tid >> 6;
    const int q = lane >> 4, ln = lane & 15;
    const int wrow = w & 1, wcol = w >> 1;
    const int m0 = blockIdx.y * 64, n0 = blockIdx.x * 64;
    const int r0 = tid >> 3, cc = (tid & 7) * 8;
    f32x4 acc[2][2] = {};
    uint4 a0 = *(const uint4*)(hist + (size_t)(m0 + r0) * H_ + cc);
    uint4 a1 = *(const uint4*)(hist + (size_t)(m0 + r0 + 32) * H_ + cc);
    uint4 b0 = *(const uint4*)(Wo + (size_t)(n0 + r0) * H_ + cc);
    uint4 b1 = *(const uint4*)(Wo + (size_t)(n0 + r0 + 32) * H_ + cc);
    for (int it = 0; it < 8; ++it) {
        __syncthreads();
        *(uint4*)&As[r0 * RS + cc] = a0;
        *(uint4*)&As[(r0 + 32) * RS + cc] = a1;
        *(uint4*)&Bs[r0 * RS + cc] = b0;
        *(uint4*)&Bs[(r0 + 32) * RS + cc] = b1;
        __syncthreads();
        if (it < 7) {
            int kt = (it + 1) * 64;
            a0 = *(const uint4*)(hist + (size_t)(m0 + r0) * H_ + kt + cc);
            a1 = *(const uint4*)(hist + (size_t)(m0 + r0 + 32) * H_ + kt + cc);
            b0 = *(const uint4*)(Wo + (size_t)(n0 + r0) * H_ + kt + cc);
            b1 = *(const uint4*)(Wo + (size_t)(n0 + r0 + 32) * H_ + kt + cc);
        }
        #pragma unroll
        for (int kh = 0; kh < 2; ++kh) {
            short8 af0 = *(const short8*)&As[(wrow * 32 + ln) * RS + kh * 32 + q * 8];
            short8 af1 = *(const short8*)&As[(wrow * 32 + 16 + ln) * RS + kh * 32 + q * 8];
            short8 bf0 = *(const short8*)&Bs[(wcol * 32 + ln) * RS + kh * 32 + q * 8];
            short8 bf1 = *(const short8*)&Bs[(wcol * 32 + 16 + ln) * RS + kh * 32 + q * 8];
            acc[0][0] = __builtin_amdgcn_mfma_f32_16x16x32_bf16(af0, bf0, acc[0][0], 0, 0, 0);
            acc[0][1] = __builtin_amdgcn_mfma_f32_16x16x32_bf16(af0, bf1, acc[0][1], 0, 0, 0);
            acc[1][0] = __builtin_amdgcn_mfma_f32_16x16x32_bf16(af1, bf0, acc[1][0], 0, 0, 0);
            acc[1][1] = __builtin_amdgcn_mfma_f32_16x16x32_bf16(af1, bf1, acc[1][1], 0, 0, 0);
        }
    }
    #pragma unroll
    for (int mt = 0; mt < 2; ++mt)
        #pragma unroll
        for (int nt = 0; nt < 2; ++nt) {
            int n = n0 + wcol * 32 + nt * 16 + ln;
            float bv = bo[n];
            #pragma unroll
            for (int r = 0; r < 4; ++r) {
                int row = m0 + wrow * 32 + mt * 16 + q * 4 + r;
                int t = row >> 10, b = row & 1023;
                out[(size_t)b * (SEQ_ * O_) + t * O_ + n] = acc[mt][nt][r] + bv;
            }
        }
}

// ---------------------------------------------------------------------------
// num head, fused fp32->bf16 A staging (once per block), B chunks from L2.
// ---------------------------------------------------------------------------
__global__ __launch_bounds__(256) void k_num_mfma(
    const float* __restrict__ enc,
    const unsigned short* __restrict__ Wseq,
    const float* __restrict__ bseq,
    const float* __restrict__ w2,
    const float* __restrict__ b2,
    float* __restrict__ out)
{
    __shared__ __align__(16) unsigned short As[64 * AR];
    __shared__ __align__(16) unsigned short Bs[64 * AR];
    const int tid = threadIdx.x;
    const int lane = tid & 63, w = tid >> 6;
    const int q = lane >> 4, ln = lane & 15;
    const int wrow = w & 1, wcol = w >> 1;
    const int m0 = blockIdx.x * 64;

    {
        const float* base = enc + (size_t)m0 * L_;
        #pragma unroll 4
        for (int it = 0; it < 16; ++it) {
            int flat = it * 1024 + tid * 4;
            int row = flat >> 8, col = flat & 255;
            float4 v = *(const float4*)(base + flat);
            ushort4 o; o.x = f2bf(v.x); o.y = f2bf(v.y); o.z = f2bf(v.z); o.w = f2bf(v.w);
            *(ushort4*)&As[row * AR + col] = o;
        }
    }
    float partial[2][4] = {};
    for (int nc = 0; nc < 8; ++nc) {
        __syncthreads();
        {
            const unsigned short* bb = Wseq + (size_t)nc * 64 * L_;
            #pragma unroll
            for (int it = 0; it < 8; ++it) {
                int flat = it * 2048 + tid * 8;
                int row = flat >> 8, col = flat & 255;
                *(uint4*)&Bs[row * AR + col] = *(const uint4*)(bb + flat);
            }
        }
        __syncthreads();
        f32x4 acc[2][2] = {};
        #pragma unroll
        for (int kt = 0; kt < 8; ++kt) {
            short8 af0 = *(const short8*)&As[(wrow * 32 + ln) * AR + kt * 32 + q * 8];
            short8 af1 = *(const short8*)&As[(wrow * 32 + 16 + ln) * AR + kt * 32 + q * 8];
            short8 bf0 = *(const short8*)&Bs[(wcol * 32 + ln) * AR + kt * 32 + q * 8];
            short8 bf1 = *(const short8*)&Bs[(wcol * 32 + 16 + ln) * AR + kt * 32 + q * 8];
            acc[0][0] = __builtin_amdgcn_mfma_f32_16x16x32_bf16(af0, bf0, acc[0][0], 0, 0, 0);
            acc[0][1] = __builtin_amdgcn_mfma_f32_16x16x32_bf16(af0, bf1, acc[0][1], 0, 0, 0);
            acc[1][0] = __builtin_amdgcn_mfma_f32_16x16x32_bf16(af1, bf0, acc[1][0], 0, 0, 0);
            acc[1][1] = __builtin_amdgcn_mfma_f32_16x16x32_bf16(af1, bf1, acc[1][1], 0, 0, 0);
        }
        #pragma unroll
        for (int nt = 0; nt < 2; ++nt) {
            int n = nc * 64 + wcol * 32 + nt * 16 + ln;
            float bs = bseq[n], wv = w2[n];
            #pragma unroll
            for (int mt = 0; mt < 2; ++mt)
                #pragma unroll
                for (int r = 0; r < 4; ++r) {
                    float v = acc[mt][nt][r] + bs;
                    v = v > 0.f ? v : 0.01f * v;
                    partial[mt][r] += v * wv;
                }
        }
    }
    __syncthreads();
    float* R = (float*)As;
    #pragma unroll
    for (int mt = 0; mt < 2; ++mt)
        #pragma unroll
        for (int r = 0; r < 4; ++r)
            R[(wrow * 32 + mt * 16 + q * 4 + r) * 33 + wcol * 16 + ln] = partial[mt][r];
    __syncthreads();
    if (tid < 64) {
        float s = b2[0];
        #pragma unroll 8
        for (int k2 = 0; k2 < 32; ++k2) s += R[tid * 33 + k2];
        out[m0 + tid] = fmaxf(s, 0.f);
    }
}

// ---------------------------------------------------------------------------
extern "C" void kernel_launch(void* const* d_in, const int* in_sizes, int n_in,
                              void* d_out, int out_size, void* d_ws, size_t ws_size,
                              hipStream_t stream) {
    const float* enc_out = (const float*)d_in[0];
    const float* enc_hid = (const float*)d_in[1];
    const float* start   = (const float*)d_in[2];
    const float* W_l2h   = (const float*)d_in[3];
    const float* b_l2h   = (const float*)d_in[4];
    const float* W_l2h2  = (const float*)d_in[5];
    const float* b_l2h2  = (const float*)d_in[6];
    const float* W_emb   = (const float*)d_in[7];
    const float* b_emb   = (const float*)d_in[8];
    const float* W_ih    = (const float*)d_in[9];
    const float* W_hh    = (const float*)d_in[10];
    const float* b_ih    = (const float*)d_in[11];
    const float* b_hh    = (const float*)d_in[12];
    const float* W_out_p = (const float*)d_in[13];
    const float* b_out_p = (const float*)d_in[14];
    const float* W_seq   = (const float*)d_in[15];
    const float* b_seq   = (const float*)d_in[16];
    const float* W_seq2  = (const float*)d_in[17];
    const float* b_seq2  = (const float*)d_in[18];

    float* out = (float*)d_out;
    float* out_dec = out;                                   // [B, SEQ, O]
    float* out_hT  = out + (size_t)B_ * SEQ_ * O_;          // [1, B, H]
    float* out_cT  = out_hT + (size_t)B_ * H_;              // [1, B, H]
    float* out_num = out_cT + (size_t)B_ * H_;              // [B, TE, 1]

    char* w = (char*)d_ws;
    unsigned short* hist = (unsigned short*)w;    w += (size_t)SEQ_ * B_ * H_ * 2;
    float* cbuf = (float*)w;                      w += (size_t)B_ * H_ * 4;
    unsigned short* h0_bf = (unsigned short*)w;   w += (size_t)B_ * H_ * 2;
    unsigned short* Wold = (unsigned short*)w;    w += (size_t)2048 * 1024 * 2;
    unsigned short* Wnew = (unsigned short*)w;    w += (size_t)2048 * 1024 * 2;
    float* bold = (float*)w;                      w += 2048 * 4;
    float* bnew = (float*)w;                      w += 2048 * 4;
    float* g0vec = (float*)w;                     w += 2048 * 4;
    unsigned* bar = (unsigned*)w;                 w += 8 * 64 * 4;
    unsigned short* Wout_bf = (unsigned short*)w; w += (size_t)O_ * H_ * 2;
    unsigned short* Wseq_bf = (unsigned short*)w; w += (size_t)H_ * L_ * 2;
    unsigned short* x0_bf = (unsigned short*)w;   w += 4096;
    unsigned short* xr0 = (unsigned short*)w;     w += (size_t)B_ * H_ * 2;
    unsigned short* xr1 = (unsigned short*)w;     w += (size_t)B_ * H_ * 2;

    // ---- weight prep ----
    k_pack_w<<<dim3(2048), dim3(256), 0, stream>>>(W_ih, W_hh, b_ih, b_hh,
                                                   Wold, bold, Wnew, bnew);
    k_cvt<<<dim3((O_ * H_ / 4 + 255) / 256), dim3(256), 0, stream>>>(W_out_p, Wout_bf, O_ * H_ / 4);
    k_cvt<<<dim3((H_ * L_ / 4 + 255) / 256), dim3(256), 0, stream>>>(W_seq, Wseq_bf, H_ * L_ / 4);
    k_x0<<<dim3(2), dim3(256), 0, stream>>>(start, W_emb, b_emb, x0_bf, bar);
    k_g0<<<dim3(2048), dim3(64), 0, stream>>>(x0_bf, Wnew, g0vec);

    // ---- init h0 (bf16), c0 (fp32) ----
    dim3 g_init(H_ / 64, B_ / 64);
    k_proj_act<<<g_init, dim3(256), 0, stream>>>(enc_hid, W_l2h,  b_l2h,  nullptr, h0_bf, B_, H_, L_);
    k_proj_act<<<g_init, dim3(256), 0, stream>>>(enc_hid, W_l2h2, b_l2h2, cbuf, nullptr, B_, H_, L_);

    // ---- 100 LSTM steps: persistent kernel, relaxed LLC barriers ----
    {
        void* kargs[] = {
            (void*)&h0_bf, (void*)&hist, (void*)&Wnew, (void*)&bnew,
            (void*)&cbuf, (void*)&g0vec, (void*)&out_hT, (void*)&out_cT, (void*)&bar
        };
        hipError_t ce = hipLaunchCooperativeKernel((const void*)k_lstm_persist,
                                                   dim3(256), dim3(256), kargs, 0, stream);
        if (ce != hipSuccess) {
            // fallback: per-step launches (round-2 path, old weight layout)
            dim3 g_lstm(2048 / 128, B_ / 64);
            for (int t = 0; t < SEQ_; ++t) {
                const unsigned short* hprev = (t == 0) ? h0_bf : hist + (size_t)(t - 1) * B_ * H_;
                const unsigned short* xs = (t == 0) ? x0_bf : ((t & 1) ? xr1 : xr0);
                int xstr = (t == 0) ? 0 : H_;
                unsigned short* xout = (t & 1) ? xr0 : xr1;
                float* hT = (t == SEQ_ - 1) ? out_hT : nullptr;
                k_lstm_v2<<<g_lstm, dim3(256), 0, stream>>>(xs, xstr, hprev, Wold, bold, cbuf,
                                                            hist + (size_t)t * B_ * H_, xout, hT);
            }
            hipMemcpyAsync(out_cT, cbuf, (size_t)B_ * H_ * 4, hipMemcpyDeviceToDevice, stream);
        }
    }

    // ---- batched output projection ----
    k_outproj_mfma<<<dim3(O_ / 64, (SEQ_ * B_) / 64), dim3(256), 0, stream>>>(hist, Wout_bf,
                                                                              b_out_p, out_dec);
    // ---- num head ----
    k_num_mfma<<<dim3((B_ * TE_) / 64), dim3(256), 0, stream>>>(enc_out, Wseq_bf, b_seq,
                                                                W_seq2, b_seq2, out_num);
}

// Round 6
// 1485.242 us; speedup vs baseline: 2.7826x; 1.3834x over previous
//
#include <hip/hip_runtime.h>
#include <hip/hip_bf16.h>

#define B_   1024
#define H_   512
#define L_   256
#define O_   128
#define SEQ_ 100
#define TE_  200
#define RS   72    // LDS row stride (ushorts) for 64-wide bf16 tiles (+8 pad)
#define AR   264   // LDS row stride (ushorts) for 256-wide bf16 tiles (+8 pad)

typedef __attribute__((ext_vector_type(8))) short short8;
typedef __attribute__((ext_vector_type(4))) float f32x4;

union U16 { unsigned long long u[2]; uint4 v; short8 s; };

// 16B LLC-direct load (bypass L1/L2 via sc0 sc1), literal byte offset.
#define LLC_LOAD16(dst, base, OFF) \
    asm volatile("global_load_dwordx4 %0, %1, off offset:" #OFF " sc0 sc1" \
                 : "=v"(dst) : "v"(base))

__device__ __forceinline__ float sigmoidf_(float x) { return 1.f / (1.f + __expf(-x)); }
__device__ __forceinline__ float tanhf_(float x) { return 1.f - 2.f / (__expf(2.f * x) + 1.f); }
__device__ __forceinline__ unsigned short f2bf(float x) {
    union { float f; unsigned u; } c; c.f = x;
    unsigned r = c.u + 0x7fffu + ((c.u >> 16) & 1u);   // RNE
    return (unsigned short)(r >> 16);
}
__device__ __forceinline__ float bf2f(unsigned short u) {
    union { unsigned u; float f; } c; c.u = (unsigned)u << 16; return c.f;
}
__device__ __forceinline__ unsigned relu2bf(unsigned x) {
    unsigned hi = x & 0xFFFF0000u, lo = x & 0x0000FFFFu;
    if (x & 0x80000000u) hi = 0u;
    if (x & 0x00008000u) lo = 0u;
    return hi | lo;
}
__device__ __forceinline__ uint4 relu8bf(uint4 v) {
    v.x = relu2bf(v.x); v.y = relu2bf(v.y); v.z = relu2bf(v.z); v.w = relu2bf(v.w);
    return v;
}

// ---------------------------------------------------------------------------
// fp32 -> bf16 convert (n4 = count/4) — used for small weights only
// ---------------------------------------------------------------------------
__global__ void k_cvt(const float* __restrict__ s, unsigned short* __restrict__ d, int n4) {
    int i = blockIdx.x * 256 + threadIdx.x;
    if (i < n4) {
        float4 v = ((const float4*)s)[i];
        ushort4 o; o.x = f2bf(v.x); o.y = f2bf(v.y); o.z = f2bf(v.z); o.w = f2bf(v.w);
        ((ushort4*)d)[i] = o;
    }
}

// ---------------------------------------------------------------------------
// Pack LSTM weights from source row sr = g*H + j into TWO layouts:
//  old (v2 fallback): row j*4+g, k 0..1023 (k<512 ih, else hh), row-major.
//  new (persistent, FRAG-MAJOR): per n-block nb=j>>4, fragment f = kc*8+xh*4+g
//  is 1024 contiguous bytes in exact MFMA lane order (ds_read conflict-free).
// ---------------------------------------------------------------------------
__global__ void k_pack_w(const float* __restrict__ Wih, const float* __restrict__ Whh,
                         const float* __restrict__ bih, const float* __restrict__ bhh,
                         unsigned short* __restrict__ Wold, float* __restrict__ bold,
                         unsigned short* __restrict__ Wnew, float* __restrict__ bnew) {
    int sr = blockIdx.x;              // 0..2047 source row: g*512 + j
    int g = sr >> 9, j = sr & 511;
    int nb = j >> 4, ln = j & 15;
    int np_old = j * 4 + g;
    int t = threadIdx.x;
    int xh = t >> 7;                  // 0: Wih half, 1: Whh half
    int t4 = (t & 127) * 4;           // k offset within half
    const float* src = (xh ? Whh : Wih) + (size_t)sr * H_ + t4;
    float4 v = *(const float4*)src;
    ushort4 o; o.x = f2bf(v.x); o.y = f2bf(v.y); o.z = f2bf(v.z); o.w = f2bf(v.w);
    *(ushort4*)(Wold + (size_t)np_old * 1024 + xh * 512 + t4) = o;
    int kc = t4 >> 5, qq = (t4 >> 3) & 3, e0 = t4 & 7;
    *(ushort4*)(Wnew + (size_t)nb * 65536
                + (size_t)((kc << 3) + (xh << 2) + g) * 512
                + (qq * 16 + ln) * 8 + e0) = o;
    if (t == 0) {
        float bv = bih[sr] + bhh[sr];
        bold[np_old] = bv;
        bnew[nb * 64 + g * 16 + ln] = bv;
    }
}

// ---------------------------------------------------------------------------
// x0relu + zero the 8 inter-block barrier counters.
// ---------------------------------------------------------------------------
__global__ void k_x0(const float* __restrict__ start, const float* __restrict__ Wemb,
                     const float* __restrict__ bemb, unsigned short* __restrict__ x0,
                     unsigned* __restrict__ bar) {
    if (blockIdx.x == 0 && threadIdx.x < 8) bar[threadIdx.x * 64] = 0u;
    int j = blockIdx.x * 256 + threadIdx.x;
    if (j < H_) {
        float s = bemb[j];
        const float* wp = Wemb + (size_t)j * O_;
        #pragma unroll 4
        for (int o = 0; o < O_; ++o) s += start[o] * wp[o];
        x0[j] = f2bf(fmaxf(s, 0.f));
    }
}

// ---------------------------------------------------------------------------
// g0vec[np] (np = nb*64 + g*16 + ln) = x0 . Wih row (frag-major read).
// ---------------------------------------------------------------------------
__global__ void k_g0(const unsigned short* __restrict__ x0,
                     const unsigned short* __restrict__ Wnew,
                     float* __restrict__ g0vec) {
    int np = blockIdx.x;
    int nb = np >> 6, f6 = np & 63;
    int g = f6 >> 4, ln = f6 & 15;
    int l = threadIdx.x;              // 64 threads; k = kc*32 + q*8 + e
    int kc = l >> 2, q = l & 3;
    const unsigned short* wr = Wnew + (size_t)nb * 65536
                             + (size_t)((kc << 3) + g) * 512 + (q * 16 + ln) * 8;
    const unsigned short* xr = x0 + kc * 32 + q * 8;
    float s = 0.f;
    #pragma unroll
    for (int e = 0; e < 8; ++e) s += bf2f(xr[e]) * bf2f(wr[e]);
    #pragma unroll
    for (int d = 32; d > 0; d >>= 1) s += __shfl_down(s, d, 64);
    if (l == 0) g0vec[np] = s;
}

// ---------------------------------------------------------------------------
// fp32 tiled init projection with leaky_relu; writes fp32 and/or bf16.
// ---------------------------------------------------------------------------
__global__ __launch_bounds__(256) void k_proj_act(
    const float* __restrict__ A, const float* __restrict__ W,
    const float* __restrict__ bias, float* __restrict__ outf,
    unsigned short* __restrict__ outbf, int M, int N, int K)
{
    __shared__ __align__(16) float As[16][68];
    __shared__ __align__(16) float Bs[16][68];
    const int tid = threadIdx.x;
    const int tx = tid & 15, ty = tid >> 4;
    const int m0 = blockIdx.y * 64, n0 = blockIdx.x * 64;
    float acc[4][4] = {};
    for (int kt = 0; kt < K; kt += 16) {
        int m = tid >> 2, k4 = (tid & 3) * 4;
        float4 av = *(const float4*)(A + (size_t)(m0 + m) * K + kt + k4);
        As[k4 + 0][m] = av.x; As[k4 + 1][m] = av.y; As[k4 + 2][m] = av.z; As[k4 + 3][m] = av.w;
        float4 bv = *(const float4*)(W + (size_t)(n0 + m) * K + kt + k4);
        Bs[k4 + 0][m] = bv.x; Bs[k4 + 1][m] = bv.y; Bs[k4 + 2][m] = bv.z; Bs[k4 + 3][m] = bv.w;
        __syncthreads();
        #pragma unroll
        for (int kk = 0; kk < 16; ++kk) {
            float4 a = *(const float4*)&As[kk][ty * 4];
            float4 b = *(const float4*)&Bs[kk][tx * 4];
            float aa[4] = {a.x, a.y, a.z, a.w}, bb[4] = {b.x, b.y, b.z, b.w};
            #pragma unroll
            for (int i = 0; i < 4; ++i)
                #pragma unroll
                for (int j = 0; j < 4; ++j) acc[i][j] += aa[i] * bb[j];
        }
        __syncthreads();
    }
    #pragma unroll
    for (int i = 0; i < 4; ++i) {
        int m = m0 + ty * 4 + i;
        #pragma unroll
        for (int j = 0; j < 4; ++j) {
            int n = n0 + tx * 4 + j;
            float v = acc[i][j] + bias[n];
            v = v > 0.f ? v : 0.01f * v;
            if (outf)  outf[(size_t)m * N + n] = v;
            if (outbf) outbf[(size_t)m * N + n] = f2bf(v);
        }
    }
}

// ---------------------------------------------------------------------------
// PERSISTENT LSTM v4: 8 waves (512 thr) -> 2 waves/SIMD for latency overlap.
// R5 lesson: relaxed-LLC sync works (3717->1637us) but 1 wave/SIMD left the
// ~700cy LLC round-trip + barrier fully exposed, and hl[64x8B]=128 VGPR made
// the compiler chunk loads into several dependent round-trips.
// v4: wave owns 16 rows (not 32): h-state = 16 x uint4 = 64 VGPR -> all 16
// LLC loads (global_load_dwordx4 sc0 sc1, literal offsets) in flight at once,
// ONE round-trip/step; 2 waves/SIMD co-schedule (m114) so one wave's wait
// hides under the other's MFMA/VALU. Barrier & stores unchanged from R5.
// ---------------------------------------------------------------------------
__global__ __launch_bounds__(512, 1) void k_lstm_persist(
    const unsigned short* __restrict__ h0,
    unsigned short* __restrict__ hist,
    const unsigned short* __restrict__ Wnew,
    const float* __restrict__ bnew,
    const float* __restrict__ c0,
    const float* __restrict__ g0vec,
    float* __restrict__ hT_out,
    float* __restrict__ cT_out,
    unsigned* __restrict__ bar)
{
    __shared__ __align__(16) unsigned short Bs[64 * 1024];   // 128 KiB
    const int tid = threadIdx.x;
    const int lane = tid & 63, wv = tid >> 6;       // 8 waves
    const int ln = lane & 15, q = lane >> 4;
    const int b = blockIdx.x;
    const int mb = b & 7, nb = b >> 3;
    const int mw = mb * 128 + wv * 16;              // 16 rows per wave

    // ---- stage frag-major weight slice: linear 128 KiB copy ----
    {
        const unsigned short* wsrc = Wnew + (size_t)nb * 65536;
        #pragma unroll
        for (int it = 0; it < 16; ++it) {
            int flat = it * 4096 + tid * 8;
            *(uint4*)&Bs[flat] = *(const uint4*)(wsrc + flat);
        }
    }

    const int j = nb * 16 + ln;
    const float b_i = bnew[nb * 64 + ln],      b_f = bnew[nb * 64 + 16 + ln];
    const float b_g = bnew[nb * 64 + 32 + ln], b_o = bnew[nb * 64 + 48 + ln];
    const float g0_i = g0vec[nb * 64 + ln],      g0_f = g0vec[nb * 64 + 16 + ln];
    const float g0_g = g0vec[nb * 64 + 32 + ln], g0_o = g0vec[nb * 64 + 48 + ln];
    const char* BsL = (const char*)Bs + lane * 16;

    float c_reg[4];
    #pragma unroll
    for (int r = 0; r < 4; ++r)
        c_reg[r] = c0[(size_t)(mw + q * 4 + r) * H_ + j];

    unsigned* cnt = bar + mb * 64;
    __syncthreads();                                 // Bs ready (block-local)

    for (int t = 0; t < SEQ_; ++t) {
        const unsigned short* hprev = (t == 0) ? h0 : hist + (size_t)(t - 1) * (B_ * H_);
        const unsigned short* apq = hprev + (size_t)(mw + ln) * H_ + q * 8;

        // ---- all 16 LLC-direct 16B loads in flight, one round-trip ----
        uint4 hl[16];
        LLC_LOAD16(hl[0],  apq, 0);    LLC_LOAD16(hl[1],  apq, 64);
        LLC_LOAD16(hl[2],  apq, 128);  LLC_LOAD16(hl[3],  apq, 192);
        LLC_LOAD16(hl[4],  apq, 256);  LLC_LOAD16(hl[5],  apq, 320);
        LLC_LOAD16(hl[6],  apq, 384);  LLC_LOAD16(hl[7],  apq, 448);
        LLC_LOAD16(hl[8],  apq, 512);  LLC_LOAD16(hl[9],  apq, 576);
        LLC_LOAD16(hl[10], apq, 640);  LLC_LOAD16(hl[11], apq, 704);
        LLC_LOAD16(hl[12], apq, 768);  LLC_LOAD16(hl[13], apq, 832);
        LLC_LOAD16(hl[14], apq, 896);  LLC_LOAD16(hl[15], apq, 960);
        asm volatile("s_waitcnt vmcnt(0)" ::: "memory");
        __builtin_amdgcn_sched_barrier(0);          // rule #18: pin MFMA after wait

        f32x4 acc[4] = {};
        if (t == 0) {
            // h-only GEMM (x-part folded into g0vec); frags xh=1
            #pragma unroll
            for (int kc = 0; kc < 16; ++kc) {
                U16 A; A.v = hl[kc];
                #pragma unroll
                for (int g = 0; g < 4; ++g) {
                    short8 bfh = *(const short8*)(BsL + (kc * 8 + 4 + g) * 1024);
                    acc[g] = __builtin_amdgcn_mfma_f32_16x16x32_bf16(A.s, bfh, acc[g], 0, 0, 0);
                }
            }
        } else {
            #pragma unroll
            for (int kc = 0; kc < 16; ++kc) {
                U16 A; A.v = hl[kc];
                U16 X; X.v = relu8bf(A.v);
                #pragma unroll
                for (int g = 0; g < 4; ++g) {
                    short8 bfx = *(const short8*)(BsL + (kc * 8 + g) * 1024);
                    short8 bfh = *(const short8*)(BsL + (kc * 8 + 4 + g) * 1024);
                    acc[g] = __builtin_amdgcn_mfma_f32_16x16x32_bf16(X.s, bfx, acc[g], 0, 0, 0);
                    acc[g] = __builtin_amdgcn_mfma_f32_16x16x32_bf16(A.s, bfh, acc[g], 0, 0, 0);
                }
            }
        }

        // ---- per-lane gate math + write-through hist stores ----
        #pragma unroll
        for (int r = 0; r < 4; ++r) {
            float iv = acc[0][r] + b_i;
            float fv = acc[1][r] + b_f;
            float gv = acc[2][r] + b_g;
            float ov = acc[3][r] + b_o;
            if (t == 0) { iv += g0_i; fv += g0_f; gv += g0_g; ov += g0_o; }
            float cn = sigmoidf_(fv) * c_reg[r] + sigmoidf_(iv) * tanhf_(gv);
            float hn = sigmoidf_(ov) * tanhf_(cn);
            c_reg[r] = cn;
            int m = mw + q * 4 + r;
            unsigned short* hp = hist + (size_t)t * (B_ * H_) + (size_t)m * H_ + j;
            unsigned hv = (unsigned)f2bf(hn);
            asm volatile("global_store_short %0, %1, off sc0 sc1"
                         :: "v"(hp), "v"(hv) : "memory");
            if (t == SEQ_ - 1) {
                hT_out[(size_t)m * H_ + j] = hn;
                cT_out[(size_t)m * H_ + j] = cn;
            }
        }

        // ---- relaxed 32-block (same-mb) barrier, no cache maintenance ----
        if (t < SEQ_ - 1) {
            asm volatile("s_waitcnt vmcnt(0)" ::: "memory");   // stores at LLC
            __syncthreads();
            if (tid == 0) {
                __hip_atomic_fetch_add(cnt, 1u, __ATOMIC_RELAXED, __HIP_MEMORY_SCOPE_SYSTEM);
                const unsigned tgt = 32u * (unsigned)(t + 1);
                while (__hip_atomic_load(cnt, __ATOMIC_RELAXED, __HIP_MEMORY_SCOPE_SYSTEM) < tgt)
                    __builtin_amdgcn_s_sleep(1);
            }
            __syncthreads();
        }
    }
}

// ---------------------------------------------------------------------------
// FALLBACK per-step LSTM (round-2 kernel, OLD weight layout) — used only if
// cooperative launch is rejected by the capture/runtime.
// ---------------------------------------------------------------------------
__global__ __launch_bounds__(256, 1) void k_lstm_v2(
    const unsigned short* __restrict__ xsrc, int x_stride,
    const unsigned short* __restrict__ hsrc,
    const unsigned short* __restrict__ Wcat,
    const float* __restrict__ biasp,
    float* __restrict__ c,
    unsigned short* __restrict__ hist_t,
    unsigned short* __restrict__ xrelu_out,
    float* __restrict__ hT_out)
{
    __shared__ __align__(16) float Gt[2][64][132];
    const int tid = threadIdx.x;
    const int lane = tid & 63, w = tid >> 6;
    const int ln = lane & 15, q = lane >> 4;
    const int i_n = w & 1, i_k = w >> 1;
    const int m0 = blockIdx.y * 64;
    const int n0 = blockIdx.x * 128;

    const unsigned short* Ab[4];
    const unsigned short* Bb[4];
    #pragma unroll
    for (int mt = 0; mt < 4; ++mt) {
        int row = m0 + mt * 16 + ln;
        Ab[mt] = (i_k == 0) ? (xsrc + (size_t)row * x_stride + q * 8)
                            : (hsrc + (size_t)row * H_ + q * 8);
    }
    #pragma unroll
    for (int nt = 0; nt < 4; ++nt)
        Bb[nt] = Wcat + (size_t)(n0 + i_n * 64 + nt * 16 + ln) * 1024 + i_k * 512 + q * 8;

    f32x4 acc[4][4] = {};
    uint4 ab[3][4], bb[3][4];

    #pragma unroll
    for (int s = 0; s < 16 + 2; ++s) {
        if (s < 16) {
            const int p = s % 3;
            #pragma unroll
            for (int mt = 0; mt < 4; ++mt)
                ab[p][mt] = *(const uint4*)(Ab[mt] + s * 32);
            #pragma unroll
            for (int nt = 0; nt < 4; ++nt)
                bb[p][nt] = *(const uint4*)(Bb[nt] + s * 32);
        }
        if (s >= 2) {
            const int p = (s - 2) % 3;
            #pragma unroll
            for (int mt = 0; mt < 4; ++mt)
                #pragma unroll
                for (int nt = 0; nt < 4; ++nt)
                    acc[mt][nt] = __builtin_amdgcn_mfma_f32_16x16x32_bf16(
                        *(const short8*)&ab[p][mt], *(const short8*)&bb[p][nt],
                        acc[mt][nt], 0, 0, 0);
        }
    }

    #pragma unroll
    for (int mt = 0; mt < 4; ++mt)
        #pragma unroll
        for (int nt = 0; nt < 4; ++nt)
            #pragma unroll
            for (int r = 0; r < 4; ++r)
                Gt[i_k][mt * 16 + q * 4 + r][i_n * 64 + nt * 16 + ln] = acc[mt][nt][r];
    __syncthreads();

    const int j0 = n0 >> 2;
    #pragma unroll
    for (int l = 0; l < 8; ++l) {
        int idx = l * 256 + tid;
        int m = idx >> 5, jj = idx & 31;
        float4 g0 = *(const float4*)&Gt[0][m][jj * 4];
        float4 g1 = *(const float4*)&Gt[1][m][jj * 4];
        float4 bv = *(const float4*)&biasp[n0 + jj * 4];
        float iv = g0.x + g1.x + bv.x;
        float fv = g0.y + g1.y + bv.y;
        float gv = g0.z + g1.z + bv.z;
        float ov = g0.w + g1.w + bv.w;
        size_t off = (size_t)(m0 + m) * H_ + (j0 + jj);
        float cv = c[off];
        float cn = sigmoidf_(fv) * cv + sigmoidf_(iv) * tanhf_(gv);
        float hn = sigmoidf_(ov) * tanhf_(cn);
        c[off] = cn;
        hist_t[off] = f2bf(hn);
        xrelu_out[off] = f2bf(fmaxf(hn, 0.f));
        if (hT_out) hT_out[off] = hn;
    }
}

// ---------------------------------------------------------------------------
// Output projection with register-prefetch. M=102400, N=128, K=512.
// ---------------------------------------------------------------------------
__global__ __launch_bounds__(256) void k_outproj_mfma(
    const unsigned short* __restrict__ hist,
    const unsigned short* __restrict__ Wo,
    const float* __restrict__ bo,
    float* __restrict__ out)
{
    __shared__ __align__(16) unsigned short As[64 * RS];
    __shared__ __align__(16) unsigned short Bs[64 * RS];
    const int tid = threadIdx.x;
    const int lane = tid & 63, w = tid >> 6;
    const int q = lane >> 4, ln = lane & 15;
    const int wrow = w & 1, wcol = w >> 1;
    const int m0 = blockIdx.y * 64, n0 = blockIdx.x * 64;
    const int r0 = tid >> 3, cc = (tid & 7) * 8;
    f32x4 acc[2][2] = {};
    uint4 a0 = *(const uint4*)(hist + (size_t)(m0 + r0) * H_ + cc);
    uint4 a1 = *(const uint4*)(hist + (size_t)(m0 + r0 + 32) * H_ + cc);
    uint4 b0 = *(const uint4*)(Wo + (size_t)(n0 + r0) * H_ + cc);
    uint4 b1 = *(const uint4*)(Wo + (size_t)(n0 + r0 + 32) * H_ + cc);
    for (int it = 0; it < 8; ++it) {
        __syncthreads();
        *(uint4*)&As[r0 * RS + cc] = a0;
        *(uint4*)&As[(r0 + 32) * RS + cc] = a1;
        *(uint4*)&Bs[r0 * RS + cc] = b0;
        *(uint4*)&Bs[(r0 + 32) * RS + cc] = b1;
        __syncthreads();
        if (it < 7) {
            int kt = (it + 1) * 64;
            a0 = *(const uint4*)(hist + (size_t)(m0 + r0) * H_ + kt + cc);
            a1 = *(const uint4*)(hist + (size_t)(m0 + r0 + 32) * H_ + kt + cc);
            b0 = *(const uint4*)(Wo + (size_t)(n0 + r0) * H_ + kt + cc);
            b1 = *(const uint4*)(Wo + (size_t)(n0 + r0 + 32) * H_ + kt + cc);
        }
        #pragma unroll
        for (int kh = 0; kh < 2; ++kh) {
            short8 af0 = *(const short8*)&As[(wrow * 32 + ln) * RS + kh * 32 + q * 8];
            short8 af1 = *(const short8*)&As[(wrow * 32 + 16 + ln) * RS + kh * 32 + q * 8];
            short8 bf0 = *(const short8*)&Bs[(wcol * 32 + ln) * RS + kh * 32 + q * 8];
            short8 bf1 = *(const short8*)&Bs[(wcol * 32 + 16 + ln) * RS + kh * 32 + q * 8];
            acc[0][0] = __builtin_amdgcn_mfma_f32_16x16x32_bf16(af0, bf0, acc[0][0], 0, 0, 0);
            acc[0][1] = __builtin_amdgcn_mfma_f32_16x16x32_bf16(af0, bf1, acc[0][1], 0, 0, 0);
            acc[1][0] = __builtin_amdgcn_mfma_f32_16x16x32_bf16(af1, bf0, acc[1][0], 0, 0, 0);
            acc[1][1] = __builtin_amdgcn_mfma_f32_16x16x32_bf16(af1, bf1, acc[1][1], 0, 0, 0);
        }
    }
    #pragma unroll
    for (int mt = 0; mt < 2; ++mt)
        #pragma unroll
        for (int nt = 0; nt < 2; ++nt) {
            int n = n0 + wcol * 32 + nt * 16 + ln;
            float bv = bo[n];
            #pragma unroll
            for (int r = 0; r < 4; ++r) {
                int row = m0 + wrow * 32 + mt * 16 + q * 4 + r;
                int t = row >> 10, b = row & 1023;
                out[(size_t)b * (SEQ_ * O_) + t * O_ + n] = acc[mt][nt][r] + bv;
            }
        }
}

// ---------------------------------------------------------------------------
// num head, fused fp32->bf16 A staging (once per block), B chunks from L2.
// ---------------------------------------------------------------------------
__global__ __launch_bounds__(256) void k_num_mfma(
    const float* __restrict__ enc,
    const unsigned short* __restrict__ Wseq,
    const float* __restrict__ bseq,
    const float* __restrict__ w2,
    const float* __restrict__ b2,
    float* __restrict__ out)
{
    __shared__ __align__(16) unsigned short As[64 * AR];
    __shared__ __align__(16) unsigned short Bs[64 * AR];
    const int tid = threadIdx.x;
    const int lane = tid & 63, w = tid >> 6;
    const int q = lane >> 4, ln = lane & 15;
    const int wrow = w & 1, wcol = w >> 1;
    const int m0 = blockIdx.x * 64;

    {
        const float* base = enc + (size_t)m0 * L_;
        #pragma unroll 4
        for (int it = 0; it < 16; ++it) {
            int flat = it * 1024 + tid * 4;
            int row = flat >> 8, col = flat & 255;
            float4 v = *(const float4*)(base + flat);
            ushort4 o; o.x = f2bf(v.x); o.y = f2bf(v.y); o.z = f2bf(v.z); o.w = f2bf(v.w);
            *(ushort4*)&As[row * AR + col] = o;
        }
    }
    float partial[2][4] = {};
    for (int nc = 0; nc < 8; ++nc) {
        __syncthreads();
        {
            const unsigned short* bb = Wseq + (size_t)nc * 64 * L_;
            #pragma unroll
            for (int it = 0; it < 8; ++it) {
                int flat = it * 2048 + tid * 8;
                int row = flat >> 8, col = flat & 255;
                *(uint4*)&Bs[row * AR + col] = *(const uint4*)(bb + flat);
            }
        }
        __syncthreads();
        f32x4 acc[2][2] = {};
        #pragma unroll
        for (int kt = 0; kt < 8; ++kt) {
            short8 af0 = *(const short8*)&As[(wrow * 32 + ln) * AR + kt * 32 + q * 8];
            short8 af1 = *(const short8*)&As[(wrow * 32 + 16 + ln) * AR + kt * 32 + q * 8];
            short8 bf0 = *(const short8*)&Bs[(wcol * 32 + ln) * AR + kt * 32 + q * 8];
            short8 bf1 = *(const short8*)&Bs[(wcol * 32 + 16 + ln) * AR + kt * 32 + q * 8];
            acc[0][0] = __builtin_amdgcn_mfma_f32_16x16x32_bf16(af0, bf0, acc[0][0], 0, 0, 0);
            acc[0][1] = __builtin_amdgcn_mfma_f32_16x16x32_bf16(af0, bf1, acc[0][1], 0, 0, 0);
            acc[1][0] = __builtin_amdgcn_mfma_f32_16x16x32_bf16(af1, bf0, acc[1][0], 0, 0, 0);
            acc[1][1] = __builtin_amdgcn_mfma_f32_16x16x32_bf16(af1, bf1, acc[1][1], 0, 0, 0);
        }
        #pragma unroll
        for (int nt = 0; nt < 2; ++nt) {
            int n = nc * 64 + wcol * 32 + nt * 16 + ln;
            float bs = bseq[n], wv = w2[n];
            #pragma unroll
            for (int mt = 0; mt < 2; ++mt)
                #pragma unroll
                for (int r = 0; r < 4; ++r) {
                    float v = acc[mt][nt][r] + bs;
                    v = v > 0.f ? v : 0.01f * v;
                    partial[mt][r] += v * wv;
                }
        }
    }
    __syncthreads();
    float* R = (float*)As;
    #pragma unroll
    for (int mt = 0; mt < 2; ++mt)
        #pragma unroll
        for (int r = 0; r < 4; ++r)
            R[(wrow * 32 + mt * 16 + q * 4 + r) * 33 + wcol * 16 + ln] = partial[mt][r];
    __syncthreads();
    if (tid < 64) {
        float s = b2[0];
        #pragma unroll 8
        for (int k2 = 0; k2 < 32; ++k2) s += R[tid * 33 + k2];
        out[m0 + tid] = fmaxf(s, 0.f);
    }
}

// ---------------------------------------------------------------------------
extern "C" void kernel_launch(void* const* d_in, const int* in_sizes, int n_in,
                              void* d_out, int out_size, void* d_ws, size_t ws_size,
                              hipStream_t stream) {
    const float* enc_out = (const float*)d_in[0];
    const float* enc_hid = (const float*)d_in[1];
    const float* start   = (const float*)d_in[2];
    const float* W_l2h   = (const float*)d_in[3];
    const float* b_l2h   = (const float*)d_in[4];
    const float* W_l2h2  = (const float*)d_in[5];
    const float* b_l2h2  = (const float*)d_in[6];
    const float* W_emb   = (const float*)d_in[7];
    const float* b_emb   = (const float*)d_in[8];
    const float* W_ih    = (const float*)d_in[9];
    const float* W_hh    = (const float*)d_in[10];
    const float* b_ih    = (const float*)d_in[11];
    const float* b_hh    = (const float*)d_in[12];
    const float* W_out_p = (const float*)d_in[13];
    const float* b_out_p = (const float*)d_in[14];
    const float* W_seq   = (const float*)d_in[15];
    const float* b_seq   = (const float*)d_in[16];
    const float* W_seq2  = (const float*)d_in[17];
    const float* b_seq2  = (const float*)d_in[18];

    float* out = (float*)d_out;
    float* out_dec = out;                                   // [B, SEQ, O]
    float* out_hT  = out + (size_t)B_ * SEQ_ * O_;          // [1, B, H]
    float* out_cT  = out_hT + (size_t)B_ * H_;              // [1, B, H]
    float* out_num = out_cT + (size_t)B_ * H_;              // [B, TE, 1]

    char* w = (char*)d_ws;
    unsigned short* hist = (unsigned short*)w;    w += (size_t)SEQ_ * B_ * H_ * 2;
    float* cbuf = (float*)w;                      w += (size_t)B_ * H_ * 4;
    unsigned short* h0_bf = (unsigned short*)w;   w += (size_t)B_ * H_ * 2;
    unsigned short* Wold = (unsigned short*)w;    w += (size_t)2048 * 1024 * 2;
    unsigned short* Wnew = (unsigned short*)w;    w += (size_t)2048 * 1024 * 2;
    float* bold = (float*)w;                      w += 2048 * 4;
    float* bnew = (float*)w;                      w += 2048 * 4;
    float* g0vec = (float*)w;                     w += 2048 * 4;
    unsigned* bar = (unsigned*)w;                 w += 8 * 64 * 4;
    unsigned short* Wout_bf = (unsigned short*)w; w += (size_t)O_ * H_ * 2;
    unsigned short* Wseq_bf = (unsigned short*)w; w += (size_t)H_ * L_ * 2;
    unsigned short* x0_bf = (unsigned short*)w;   w += 4096;
    unsigned short* xr0 = (unsigned short*)w;     w += (size_t)B_ * H_ * 2;
    unsigned short* xr1 = (unsigned short*)w;     w += (size_t)B_ * H_ * 2;

    // ---- weight prep ----
    k_pack_w<<<dim3(2048), dim3(256), 0, stream>>>(W_ih, W_hh, b_ih, b_hh,
                                                   Wold, bold, Wnew, bnew);
    k_cvt<<<dim3((O_ * H_ / 4 + 255) / 256), dim3(256), 0, stream>>>(W_out_p, Wout_bf, O_ * H_ / 4);
    k_cvt<<<dim3((H_ * L_ / 4 + 255) / 256), dim3(256), 0, stream>>>(W_seq, Wseq_bf, H_ * L_ / 4);
    k_x0<<<dim3(2), dim3(256), 0, stream>>>(start, W_emb, b_emb, x0_bf, bar);
    k_g0<<<dim3(2048), dim3(64), 0, stream>>>(x0_bf, Wnew, g0vec);

    // ---- init h0 (bf16), c0 (fp32) ----
    dim3 g_init(H_ / 64, B_ / 64);
    k_proj_act<<<g_init, dim3(256), 0, stream>>>(enc_hid, W_l2h,  b_l2h,  nullptr, h0_bf, B_, H_, L_);
    k_proj_act<<<g_init, dim3(256), 0, stream>>>(enc_hid, W_l2h2, b_l2h2, cbuf, nullptr, B_, H_, L_);

    // ---- 100 LSTM steps: persistent kernel, relaxed LLC barriers ----
    {
        void* kargs[] = {
            (void*)&h0_bf, (void*)&hist, (void*)&Wnew, (void*)&bnew,
            (void*)&cbuf, (void*)&g0vec, (void*)&out_hT, (void*)&out_cT, (void*)&bar
        };
        hipError_t ce = hipLaunchCooperativeKernel((const void*)k_lstm_persist,
                                                   dim3(256), dim3(512), kargs, 0, stream);
        if (ce != hipSuccess) {
            // fallback: per-step launches (round-2 path, old weight layout)
            dim3 g_lstm(2048 / 128, B_ / 64);
            for (int t = 0; t < SEQ_; ++t) {
                const unsigned short* hprev = (t == 0) ? h0_bf : hist + (size_t)(t - 1) * B_ * H_;
                const unsigned short* xs = (t == 0) ? x0_bf : ((t & 1) ? xr1 : xr0);
                int xstr = (t == 0) ? 0 : H_;
                unsigned short* xout = (t & 1) ? xr0 : xr1;
                float* hT = (t == SEQ_ - 1) ? out_hT : nullptr;
                k_lstm_v2<<<g_lstm, dim3(256), 0, stream>>>(xs, xstr, hprev, Wold, bold, cbuf,
                                                            hist + (size_t)t * B_ * H_, xout, hT);
            }
            hipMemcpyAsync(out_cT, cbuf, (size_t)B_ * H_ * 4, hipMemcpyDeviceToDevice, stream);
        }
    }

    // ---- batched output projection ----
    k_outproj_mfma<<<dim3(O_ / 64, (SEQ_ * B_) / 64), dim3(256), 0, stream>>>(hist, Wout_bf,
                                                                              b_out_p, out_dec);
    // ---- num head ----
    k_num_mfma<<<dim3((B_ * TE_) / 64), dim3(256), 0, stream>>>(enc_out, Wseq_bf, b_seq,
                                                                W_seq2, b_seq2, out_num);
}